// Round 11
// baseline (220.172 us; speedup 1.0000x reference)
//
#include <hip/hip_runtime.h>

#define B_ 64
#define LC 2048
#define LQ 256
#define DD 128

typedef __bf16 bf16;
typedef __bf16 bf16x8 __attribute__((ext_vector_type(8)));
typedef __bf16 bf16x4 __attribute__((ext_vector_type(4)));
typedef float f32x4 __attribute__((ext_vector_type(4)));

#define MFMA16(a, b, c) __builtin_amdgcn_mfma_f32_16x16x32_bf16((a), (b), (c), 0, 0, 0)

// Panel layouts (bf16, chunk = 512 elems = 1KB), within-chunk LANE-LINEAR:
// fragment for MFMA-lane l sits at elems [l*8 .. l*8+7].
//  Cwp   [b][cb  (LC/16)][ks 4 ][512]  frag(lr,lg): c=cb*16+lr, d=ks*32+lg*8+i  (*w4mlu)
//  Qbp   [b][qb  (LQ/16)][ks 4 ][512]  frag(lr,lg): q=qb*16+lr, d=ks*32+lg*8+i
//  QbTp  [b][ks  (LQ/32)][dt 8 ][512]  frag(lr,lg): d=dt*16+lr, q=ks*32+lg*8+i
//  CbTmp [b][cb32(LC/32)][d 128][32 ]  elem (c=cb32*32+ci, d) = bf16(C*Cmask)^T
//  Pp    [b][cb  (LC/16)][ks 8 ][512]  frag(lr,lg): c=cb*16+lr, q=ks*32+lg*8+i (UNmasked)
//  MTpn  [b][ks 8][dt 8][512]          frag(lr,lg): d=dt*16+lr, q=ks*32+lg*8+i (Linv folded)

// ---------------------------------------------------------------------------
// K1 (merged preps): blocks 0..2047 = C path; 2048..2303 = Q path. (unchanged)
// ---------------------------------------------------------------------------
__global__ __launch_bounds__(256) void k_prep(const float* __restrict__ C,
    const float* __restrict__ Q, const float* __restrict__ Cmask,
    const float* __restrict__ w4C, const float* __restrict__ w4Q,
    const float* __restrict__ w4mlu,
    bf16* __restrict__ Cwp, bf16* __restrict__ CbTmp,
    bf16* __restrict__ Qbp, bf16* __restrict__ QbTp,
    float* __restrict__ sub0, float* __restrict__ sub1, float* __restrict__ out)
{
    __shared__ float lds[64][DD + 4];
    __shared__ float ldsM[64];
    int t = threadIdx.x;
    if (blockIdx.x < 2048) {
        int b = blockIdx.x >> 5, ct = blockIdx.x & 31;
        int c0 = ct * 64;
        int r = t >> 2, cb = (t & 3) * 32;
        size_t rowoff = ((size_t)(b * LC + c0 + r)) * DD + cb;
        const float4* src = (const float4*)(C + rowoff);
        if ((t & 3) == 0) ldsM[r] = Cmask[b * LC + c0 + r];
        float s0 = 0.f;
#pragma unroll
        for (int i = 0; i < 8; ++i) {
            float4 v = src[i];
            int d = cb + i * 4;
            lds[r][d] = v.x; lds[r][d + 1] = v.y; lds[r][d + 2] = v.z; lds[r][d + 3] = v.w;
            s0 += v.x * w4C[d] + v.y * w4C[d + 1] + v.z * w4C[d + 2] + v.w * w4C[d + 3];
        }
        s0 += __shfl_xor(s0, 1);
        s0 += __shfl_xor(s0, 2);
        if ((t & 3) == 0) sub0[b * LC + c0 + r] = s0;
        __syncthreads();

#pragma unroll
        for (int p = 0; p < 4; ++p) {
            int idx = p * 256 + t;
            int chunk = idx >> 6, w = idx & 63;
            int cb_l = chunk >> 2, ks = chunk & 3;
            int lr = w & 15, lg = w >> 4;
            int c_l = cb_l * 16 + lr, d0 = ks * 32 + lg * 8;
            bf16x8 v;
#pragma unroll
            for (int j = 0; j < 8; ++j) v[j] = (bf16)(lds[c_l][d0 + j] * w4mlu[d0 + j]);
            size_t off = ((size_t)((b * 128 + ct * 4 + cb_l) * 4 + ks)) * 512 + w * 8;
            *(bf16x8*)(Cwp + off) = v;
        }
#pragma unroll
        for (int p = 0; p < 4; ++p) {
            int idx = p * 256 + t;
            int cb32 = idx >> 9, rem = idx & 511;
            int d = rem >> 2, lg = rem & 3;
            int cl0 = cb32 * 32 + lg * 8;
            bf16x8 v;
#pragma unroll
            for (int j = 0; j < 8; ++j) v[j] = (bf16)(lds[cl0 + j][d] * ldsM[cl0 + j]);
            size_t off = ((size_t)((b * 64 + ct * 2 + cb32) * 128 + d)) * 32 + lg * 8;
            *(bf16x8*)(CbTmp + off) = v;
        }
#pragma unroll
        for (int p = 0; p < 8; ++p) {
            int d = p * 16 + (t >> 4);
            int cl = (t & 15) * 4;
            float4 v = {lds[cl][d], lds[cl + 1][d], lds[cl + 2][d], lds[cl + 3][d]};
            *(float4*)(out + ((size_t)(b * 512 + d)) * LC + c0 + cl) = v;
        }
    } else {
        int idx0 = blockIdx.x - 2048;
        int b = idx0 >> 2, qt = idx0 & 3;
        int q0 = qt * 64;
        bf16* ldsb = (bf16*)lds;   // reuse as bf16 [64][132]
        int r = t >> 2, cb = (t & 3) * 32;
        size_t rowoff = ((size_t)(b * LQ + q0 + r)) * DD + cb;
        const float4* src = (const float4*)(Q + rowoff);
        float s1 = 0.f;
#pragma unroll
        for (int i = 0; i < 8; ++i) {
            float4 v = src[i];
            int d = cb + i * 4;
            ldsb[r * 132 + d] = (bf16)v.x; ldsb[r * 132 + d + 1] = (bf16)v.y;
            ldsb[r * 132 + d + 2] = (bf16)v.z; ldsb[r * 132 + d + 3] = (bf16)v.w;
            s1 += v.x * w4Q[d] + v.y * w4Q[d + 1] + v.z * w4Q[d + 2] + v.w * w4Q[d + 3];
        }
        s1 += __shfl_xor(s1, 1);
        s1 += __shfl_xor(s1, 2);
        if ((t & 3) == 0) sub1[b * LQ + q0 + r] = s1;
        __syncthreads();

#pragma unroll
        for (int p = 0; p < 4; ++p) {
            int idx = p * 256 + t;
            int chunk = idx >> 6, w = idx & 63;
            int qb_l = chunk >> 2, ks = chunk & 3;
            int lr = w & 15, lg = w >> 4;
            bf16x8 v = *(bf16x8*)&ldsb[(qb_l * 16 + lr) * 132 + ks * 32 + lg * 8];
            size_t off = ((size_t)((b * 16 + qt * 4 + qb_l) * 4 + ks)) * 512 + w * 8;
            *(bf16x8*)(Qbp + off) = v;
        }
#pragma unroll
        for (int p = 0; p < 4; ++p) {
            int idx = p * 256 + t;
            int chunk = idx >> 6, w = idx & 63;
            int ks_l = chunk >> 3, dt = chunk & 7;
            int lr = w & 15, lg = w >> 4;
            int d = dt * 16 + lr, ql = ks_l * 32 + lg * 8;
            bf16x8 v;
#pragma unroll
            for (int j = 0; j < 8; ++j) v[j] = ldsb[(ql + j) * 132 + d];
            size_t off = ((size_t)((b * 8 + qt * 2 + ks_l) * 8 + dt)) * 512 + w * 8;
            *(bf16x8*)(QbTp + off) = v;
        }
    }
}

// ---------------------------------------------------------------------------
// K2 (fused k_s + k_m + k_m2): per block = (32 q) x (all 2048 c), loop 16 ctiles.
//   Per ctile: S = Cw@Qb^T + subs + bias; P = Qm*exp(S-8) -> Pp panel store;
//   accumulate accM += CbTm(d,c) @ P^T(c,q) from ldsPT; colacc (masked colsums)
//   and Rpart rowsum partials. Finale: Linv from colacc (block-local!), scale
//   accM, write MTpn panels. grid (8 qs, B), 256 thr (4 waves).
// ---------------------------------------------------------------------------
__global__ __launch_bounds__(256) void k_sm(const bf16* __restrict__ Cwp,
    const bf16* __restrict__ Qbp, const bf16* __restrict__ CbTmp,
    const float* __restrict__ sub0, const float* __restrict__ sub1,
    const float* __restrict__ Qmask, const float* __restrict__ Cmask,
    const float* __restrict__ bias,
    bf16* __restrict__ Pp, bf16* __restrict__ MTpn, float* __restrict__ Rpart)
{
    __shared__ bf16 ldsP[128][42];    // [c_local][q_local 32] (+pad); reused as ldsMT [d][q]
    __shared__ bf16 ldsPT[32][136];   // [q_local][c_local 128] (+pad)
    __shared__ float ldsLred[4][32];
    int b = blockIdx.y, qs = blockIdx.x;
    int t = threadIdx.x, wid = t >> 6, lane = t & 63;
    int lr = lane & 15, lg = lane >> 4;

    float biasv = bias[0];
    float s1v[2], qmv[2];
#pragma unroll
    for (int ct = 0; ct < 2; ++ct) {
        int q = qs * 32 + ct * 16 + lr;
        s1v[ct] = sub1[b * LQ + q] + biasv;
        qmv[ct] = Qmask[b * LQ + q];
    }

    f32x4 accM[2][2];
#pragma unroll
    for (int r2 = 0; r2 < 2; ++r2)
#pragma unroll
        for (int c2 = 0; c2 < 2; ++c2) accM[r2][c2] = (f32x4){0.f, 0.f, 0.f, 0.f};
    float colacc[2] = {0.f, 0.f};

    for (int cc = 0; cc < 16; ++cc) {
        // ---- S GEMM: 128c x 32q ----
        f32x4 acc[2][2];
#pragma unroll
        for (int r2 = 0; r2 < 2; ++r2)
#pragma unroll
            for (int c2 = 0; c2 < 2; ++c2) acc[r2][c2] = (f32x4){0.f, 0.f, 0.f, 0.f};
        const bf16* Ab = Cwp + ((size_t)((b * 128 + cc * 8 + wid * 2) * 4)) * 512 + lane * 8;
        const bf16* Bb = Qbp + ((size_t)((b * 16 + qs * 2) * 4)) * 512 + lane * 8;
#pragma unroll
        for (int ks = 0; ks < 4; ++ks) {
            bf16x8 a0 = *(const bf16x8*)(Ab + (size_t)ks * 512);
            bf16x8 a1 = *(const bf16x8*)(Ab + (size_t)(4 + ks) * 512);
#pragma unroll
            for (int ct = 0; ct < 2; ++ct) {
                bf16x8 bb = *(const bf16x8*)(Bb + (size_t)(ct * 4 + ks) * 512);
                acc[0][ct] = MFMA16(a0, bb, acc[0][ct]);
                acc[1][ct] = MFMA16(a1, bb, acc[1][ct]);
            }
        }

        float sub0v[2][4], cmv[2][4];
#pragma unroll
        for (int rt = 0; rt < 2; ++rt)
#pragma unroll
            for (int j = 0; j < 4; ++j) {
                int idx = b * LC + cc * 128 + wid * 32 + rt * 16 + lg * 4 + j;
                sub0v[rt][j] = sub0[idx];
                cmv[rt][j] = Cmask[idx];
            }

        // wait for previous iteration's ldsP/ldsPT consumers
        __syncthreads();

        float rsum[2][4] = {};
#pragma unroll
        for (int ct = 0; ct < 2; ++ct) {
            float colsum = 0.f;
#pragma unroll
            for (int rt = 0; rt < 2; ++rt) {
                bf16x4 ptv;
#pragma unroll
                for (int j = 0; j < 4; ++j) {
                    float S = acc[rt][ct][j] + sub0v[rt][j] + s1v[ct];
                    float Pv = __expf(S - 8.0f) * qmv[ct];
                    rsum[rt][j] += Pv;
                    colsum += Pv * cmv[rt][j];
                    bf16 pb = (bf16)Pv;
                    ldsP[wid * 32 + rt * 16 + lg * 4 + j][ct * 16 + lr] = pb;
                    ptv[j] = pb;
                }
                *(bf16x4*)&ldsPT[ct * 16 + lr][wid * 32 + rt * 16 + lg * 4] = ptv;
            }
            colsum += __shfl_xor(colsum, 16);
            colsum += __shfl_xor(colsum, 32);
            colacc[ct] += colsum;
        }
#pragma unroll
        for (int rt = 0; rt < 2; ++rt)
#pragma unroll
            for (int j = 0; j < 4; ++j) {
                float s = rsum[rt][j];
                s += __shfl_xor(s, 1);
                s += __shfl_xor(s, 2);
                s += __shfl_xor(s, 4);
                s += __shfl_xor(s, 8);
                if (lr == 0)
                    Rpart[((size_t)(b * 8 + qs)) * LC + cc * 128 + wid * 32 + rt * 16 + lg * 4 + j] = s;
            }
        __syncthreads();

        // ---- Pp panel store (8 chunks of this ctile, ks-slot = qs) ----
#pragma unroll
        for (int p = 0; p < 2; ++p) {
            int w = (t & 31) * 2 + p;
            int cb_l = t >> 5;
            bf16x8 v = *(bf16x8*)&ldsP[cb_l * 16 + (w & 15)][(w >> 4) * 8];
            size_t off = ((size_t)((b * 128 + cc * 8 + cb_l) * 8 + qs)) * 512 + w * 8;
            *(bf16x8*)(Pp + off) = v;
        }

        // ---- M GEMM accumulate: accM += CbTm[d][c-slice] @ P^T ----
        const bf16* Am = CbTmp + ((size_t)(b * 64 + cc * 4) * 128 + wid * 32 + lr) * 32 + lg * 8;
#pragma unroll
        for (int kf = 0; kf < 4; ++kf) {
            bf16x8 a0 = *(const bf16x8*)(Am + (size_t)kf * 4096);
            bf16x8 a1 = *(const bf16x8*)(Am + (size_t)kf * 4096 + 512);
#pragma unroll
            for (int c2 = 0; c2 < 2; ++c2) {
                bf16x8 bb = *(bf16x8*)&ldsPT[c2 * 16 + lr][kf * 32 + lg * 8];
                accM[0][c2] = MFMA16(a0, bb, accM[0][c2]);
                accM[1][c2] = MFMA16(a1, bb, accM[1][c2]);
            }
        }
    }

    // ---- Finale: Linv, scale accM, MTpn panel store ----
    __syncthreads();
    if (lg == 0) {
        ldsLred[wid][lr] = colacc[0];
        ldsLred[wid][16 + lr] = colacc[1];
    }
    __syncthreads();
    float linv[2];
#pragma unroll
    for (int ct = 0; ct < 2; ++ct) {
        int ql = ct * 16 + lr;
        float L = ldsLred[0][ql] + ldsLred[1][ql] + ldsLred[2][ql] + ldsLred[3][ql];
        linv[ct] = 1.0f / fmaxf(L, 1e-30f);
    }
    // reuse ldsP as ldsMT [d 128][q 32(+pad 42)]
#pragma unroll
    for (int r2 = 0; r2 < 2; ++r2)
#pragma unroll
        for (int c2 = 0; c2 < 2; ++c2)
#pragma unroll
            for (int j = 0; j < 4; ++j)
                ldsP[wid * 32 + r2 * 16 + lg * 4 + j][c2 * 16 + lr] =
                    (bf16)(accM[r2][c2][j] * linv[c2]);
    __syncthreads();
#pragma unroll
    for (int p = 0; p < 2; ++p) {
        int w = (t & 31) * 2 + p;
        int dt = t >> 5;
        bf16x8 v = *(bf16x8*)&ldsP[dt * 16 + (w & 15)][(w >> 4) * 8];
        *(bf16x8*)(MTpn + ((size_t)((b * 8 + qs) * 8 + dt)) * 512 + w * 8) = v;
    }
}

// ---------------------------------------------------------------------------
// K3: A = Rinv*(P@Qb), Bt = Rinv*(P@M). (unchanged except Rpart has 8 slices)
// grid (32 ctile, B), 256 thr (4 waves)
// ---------------------------------------------------------------------------
__global__ __launch_bounds__(256) void k_out(const bf16* __restrict__ Pp,
    const bf16* __restrict__ QbTp, const bf16* __restrict__ MTpn,
    const float* __restrict__ Rpart, float* __restrict__ out)
{
    __shared__ f32x4 smem4[2304];                       // 36864 B
    bf16* stage = (bf16*)smem4;                         // stage[2][8192] (32 KB)
    bf16 (*ldsA)[72] = (bf16(*)[72])smem4;              // epilogue-only (union)
    bf16 (*ldsB)[72] = (bf16(*)[72])((char*)smem4 + 18432);

    int b = blockIdx.y, ctile = blockIdx.x;
    int t = threadIdx.x, wid = t >> 6, lane = t & 63;
    int lr = lane & 15, lg = lane >> 4;
    int c0 = ctile * 64;

    const bf16* gsrc = (wid < 2 ? QbTp : MTpn) + (size_t)b * 32768
                       + (size_t)(wid & 1) * 2048 + lane * 8;
    int ldst = wid * 2048 + lane * 8;

    f32x4 rs = (f32x4){0.f, 0.f, 0.f, 0.f};
#pragma unroll
    for (int s = 0; s < 8; ++s)
        rs += *(const f32x4*)(Rpart + ((size_t)(b * 8 + s)) * LC + c0 + wid * 16 + lg * 4);
    f32x4 rv;
#pragma unroll
    for (int j = 0; j < 4; ++j) rv[j] = 1.0f / fmaxf(rs[j], 1e-30f);

    f32x4 accA[8], accB[8];
#pragma unroll
    for (int dt = 0; dt < 8; ++dt) {
        accA[dt] = (f32x4){0.f, 0.f, 0.f, 0.f};
        accB[dt] = (f32x4){0.f, 0.f, 0.f, 0.f};
    }
    const bf16* Ab = Pp + ((size_t)((b * 128 + ctile * 4 + wid) * 8)) * 512 + lane * 8;

    {
        bf16x8 g0 = *(const bf16x8*)(gsrc);
        bf16x8 g1 = *(const bf16x8*)(gsrc + 512);
        bf16x8 g2 = *(const bf16x8*)(gsrc + 1024);
        bf16x8 g3 = *(const bf16x8*)(gsrc + 1536);
        *(bf16x8*)&stage[ldst]        = g0;
        *(bf16x8*)&stage[ldst + 512]  = g1;
        *(bf16x8*)&stage[ldst + 1024] = g2;
        *(bf16x8*)&stage[ldst + 1536] = g3;
    }
    __syncthreads();

    for (int ks = 0; ks < 8; ++ks) {
        int cur = (ks & 1) * 8192;
        bf16x8 g0, g1, g2, g3;
        if (ks < 7) {
            const bf16* gs = gsrc + (size_t)(ks + 1) * 4096;
            g0 = *(const bf16x8*)(gs);
            g1 = *(const bf16x8*)(gs + 512);
            g2 = *(const bf16x8*)(gs + 1024);
            g3 = *(const bf16x8*)(gs + 1536);
        }
        bf16x8 a = *(const bf16x8*)(Ab + (size_t)ks * 512);
        int foff = cur + lane * 8;
#pragma unroll
        for (int dt = 0; dt < 8; ++dt) {
            bf16x8 bq = *(bf16x8*)&stage[foff + dt * 512];
            bf16x8 bm = *(bf16x8*)&stage[foff + 4096 + dt * 512];
            accA[dt] = MFMA16(a, bq, accA[dt]);
            accB[dt] = MFMA16(a, bm, accB[dt]);
        }
        if (ks < 7) {
            int nb = cur ^ 8192;
            *(bf16x8*)&stage[nb + ldst]        = g0;
            *(bf16x8*)&stage[nb + ldst + 512]  = g1;
            *(bf16x8*)&stage[nb + ldst + 1024] = g2;
            *(bf16x8*)&stage[nb + ldst + 1536] = g3;
        }
        __syncthreads();
    }

#pragma unroll
    for (int dt = 0; dt < 8; ++dt) {
        f32x4 a4 = accA[dt] * rv;
        f32x4 b4 = accB[dt] * rv;
        bf16x4 pa = { (bf16)a4[0], (bf16)a4[1], (bf16)a4[2], (bf16)a4[3] };
        bf16x4 pb = { (bf16)b4[0], (bf16)b4[1], (bf16)b4[2], (bf16)b4[3] };
        *(bf16x4*)&ldsA[dt * 16 + lr][wid * 16 + lg * 4] = pa;
        *(bf16x4*)&ldsB[dt * 16 + lr][wid * 16 + lg * 4] = pb;
    }
    __syncthreads();

    float* obase = out + ((size_t)b * 512) * LC;
#pragma unroll
    for (int pass = 0; pass < 8; ++pass) {
        int d = pass * 16 + (t >> 4);
        int cq = (t & 15) * 4;
        bf16x4 av = *(bf16x4*)&ldsA[d][cq];
        bf16x4 bv = *(bf16x4*)&ldsB[d][cq];
        f32x4 c4 = *(const f32x4*)(obase + (size_t)d * LC + c0 + cq);
        f32x4 a4 = {(float)av[0], (float)av[1], (float)av[2], (float)av[3]};
        f32x4 b4 = {(float)bv[0], (float)bv[1], (float)bv[2], (float)bv[3]};
        __builtin_nontemporal_store(a4, (f32x4*)(obase + (size_t)(128 + d) * LC + c0 + cq));
        __builtin_nontemporal_store(c4 * a4, (f32x4*)(obase + (size_t)(256 + d) * LC + c0 + cq));
        __builtin_nontemporal_store(c4 * b4, (f32x4*)(obase + (size_t)(384 + d) * LC + c0 + cq));
    }
}

// ---------------------------------------------------------------------------
extern "C" void kernel_launch(void* const* d_in, const int* in_sizes, int n_in,
                              void* d_out, int out_size, void* d_ws, size_t ws_size,
                              hipStream_t stream)
{
    const float* C     = (const float*)d_in[0];
    const float* Q     = (const float*)d_in[1];
    const float* Cmask = (const float*)d_in[2];
    const float* Qmask = (const float*)d_in[3];
    const float* w4C   = (const float*)d_in[4];
    const float* w4Q   = (const float*)d_in[5];
    const float* w4mlu = (const float*)d_in[6];
    const float* bias  = (const float*)d_in[7];
    float* out = (float*)d_out;

    char* ws = (char*)d_ws;
    size_t off = 0;
    auto alloc = [&](size_t bytes) -> char* {
        char* p = ws + off;
        off += (bytes + 255) & ~(size_t)255;
        return p;
    };
    bf16* Cwp   = (bf16*)alloc((size_t)B_ * LC * DD * 2);
    bf16* CbTmp = (bf16*)alloc((size_t)B_ * LC * DD * 2);
    bf16* Qbp   = (bf16*)alloc((size_t)B_ * LQ * DD * 2);
    bf16* QbTp  = (bf16*)alloc((size_t)B_ * LQ * DD * 2);
    bf16* Pp    = (bf16*)alloc((size_t)B_ * LC * LQ * 2);
    bf16* MTpn  = (bf16*)alloc((size_t)B_ * DD * LQ * 2);
    float* sub0 = (float*)alloc((size_t)B_ * LC * 4);
    float* sub1 = (float*)alloc((size_t)B_ * LQ * 4);
    float* Rpart = (float*)alloc((size_t)B_ * 8 * LC * 4);
    (void)ws_size; (void)in_sizes; (void)n_in; (void)out_size;

    hipLaunchKernelGGL(k_prep, dim3(2304), dim3(256), 0, stream,
                       C, Q, Cmask, w4C, w4Q, w4mlu, Cwp, CbTmp, Qbp, QbTp, sub0, sub1, out);
    hipLaunchKernelGGL(k_sm, dim3(8, B_), dim3(256), 0, stream,
                       Cwp, Qbp, CbTmp, sub0, sub1, Qmask, Cmask, bias, Pp, MTpn, Rpart);
    hipLaunchKernelGGL(k_out, dim3(32, B_), dim3(256), 0, stream,
                       Pp, QbTp, MTpn, Rpart, out);
}

// Round 12
// 198.528 us; speedup vs baseline: 1.1090x; 1.1090x over previous
//
#include <hip/hip_runtime.h>

#define B_ 64
#define LC 2048
#define LQ 256
#define DD 128

typedef __bf16 bf16;
typedef __bf16 bf16x8 __attribute__((ext_vector_type(8)));
typedef __bf16 bf16x4 __attribute__((ext_vector_type(4)));
typedef float f32x4 __attribute__((ext_vector_type(4)));

#define MFMA16(a, b, c) __builtin_amdgcn_mfma_f32_16x16x32_bf16((a), (b), (c), 0, 0, 0)

// Panel layouts (bf16, chunk = 512 elems = 1KB), within-chunk LANE-LINEAR:
// fragment for MFMA-lane l sits at elems [l*8 .. l*8+7].
//  Cwp   [b][cb  (LC/16)][ks 4 ][512]  frag(lr,lg): c=cb*16+lr, d=ks*32+lg*8+i  (*w4mlu)
//  Qbp   [b][qb  (LQ/16)][ks 4 ][512]  frag(lr,lg): q=qb*16+lr, d=ks*32+lg*8+i
//  QbTp  [b][ks  (LQ/32)][dt 8 ][512]  frag(lr,lg): d=dt*16+lr, q=ks*32+lg*8+i
//  CbTmp [b][cb32(LC/32)][d 128][32 ]  elem (c=cb32*32+ci, d) = bf16(C*Cmask)^T
//  Pp    [b][cb  (LC/16)][ks 8 ][512]  frag(lr,lg): c=cb*16+lr, q=ks*32+lg*8+i (UNmasked)
//  MTpn  [b][ks 8][dt 8][512]          frag(lr,lg): d=dt*16+lr, q=ks*32+lg*8+i (Linv folded)
// XCD swizzle (k_s/k_m/k_out): 1-D grid, xcd = id&7, same-b blocks co-located
// on one XCD so shared panels (QbTp/MTpn/Qbp/CbTmp/Rpart) are L2-hits.

// ---------------------------------------------------------------------------
// K1 (merged preps): blocks 0..2047 = C path; 2048..2303 = Q path.
// ---------------------------------------------------------------------------
__global__ __launch_bounds__(256) void k_prep(const float* __restrict__ C,
    const float* __restrict__ Q, const float* __restrict__ Cmask,
    const float* __restrict__ w4C, const float* __restrict__ w4Q,
    const float* __restrict__ w4mlu,
    bf16* __restrict__ Cwp, bf16* __restrict__ CbTmp,
    bf16* __restrict__ Qbp, bf16* __restrict__ QbTp,
    float* __restrict__ sub0, float* __restrict__ sub1, float* __restrict__ out)
{
    __shared__ float lds[64][DD + 4];
    __shared__ float ldsM[64];
    int t = threadIdx.x;
    if (blockIdx.x < 2048) {
        int b = blockIdx.x >> 5, ct = blockIdx.x & 31;
        int c0 = ct * 64;
        int r = t >> 2, cb = (t & 3) * 32;
        size_t rowoff = ((size_t)(b * LC + c0 + r)) * DD + cb;
        const float4* src = (const float4*)(C + rowoff);
        if ((t & 3) == 0) ldsM[r] = Cmask[b * LC + c0 + r];
        float s0 = 0.f;
#pragma unroll
        for (int i = 0; i < 8; ++i) {
            float4 v = src[i];
            int d = cb + i * 4;
            lds[r][d] = v.x; lds[r][d + 1] = v.y; lds[r][d + 2] = v.z; lds[r][d + 3] = v.w;
            s0 += v.x * w4C[d] + v.y * w4C[d + 1] + v.z * w4C[d + 2] + v.w * w4C[d + 3];
        }
        s0 += __shfl_xor(s0, 1);
        s0 += __shfl_xor(s0, 2);
        if ((t & 3) == 0) sub0[b * LC + c0 + r] = s0;
        __syncthreads();

#pragma unroll
        for (int p = 0; p < 4; ++p) {
            int idx = p * 256 + t;
            int chunk = idx >> 6, w = idx & 63;
            int cb_l = chunk >> 2, ks = chunk & 3;
            int lr = w & 15, lg = w >> 4;
            int c_l = cb_l * 16 + lr, d0 = ks * 32 + lg * 8;
            bf16x8 v;
#pragma unroll
            for (int j = 0; j < 8; ++j) v[j] = (bf16)(lds[c_l][d0 + j] * w4mlu[d0 + j]);
            size_t off = ((size_t)((b * 128 + ct * 4 + cb_l) * 4 + ks)) * 512 + w * 8;
            *(bf16x8*)(Cwp + off) = v;
        }
#pragma unroll
        for (int p = 0; p < 4; ++p) {
            int idx = p * 256 + t;
            int cb32 = idx >> 9, rem = idx & 511;
            int d = rem >> 2, lg = rem & 3;
            int cl0 = cb32 * 32 + lg * 8;
            bf16x8 v;
#pragma unroll
            for (int j = 0; j < 8; ++j) v[j] = (bf16)(lds[cl0 + j][d] * ldsM[cl0 + j]);
            size_t off = ((size_t)((b * 64 + ct * 2 + cb32) * 128 + d)) * 32 + lg * 8;
            *(bf16x8*)(CbTmp + off) = v;
        }
#pragma unroll
        for (int p = 0; p < 8; ++p) {
            int d = p * 16 + (t >> 4);
            int cl = (t & 15) * 4;
            float4 v = {lds[cl][d], lds[cl + 1][d], lds[cl + 2][d], lds[cl + 3][d]};
            *(float4*)(out + ((size_t)(b * 512 + d)) * LC + c0 + cl) = v;
        }
    } else {
        int idx0 = blockIdx.x - 2048;
        int b = idx0 >> 2, qt = idx0 & 3;
        int q0 = qt * 64;
        bf16* ldsb = (bf16*)lds;   // reuse as bf16 [64][132]
        int r = t >> 2, cb = (t & 3) * 32;
        size_t rowoff = ((size_t)(b * LQ + q0 + r)) * DD + cb;
        const float4* src = (const float4*)(Q + rowoff);
        float s1 = 0.f;
#pragma unroll
        for (int i = 0; i < 8; ++i) {
            float4 v = src[i];
            int d = cb + i * 4;
            ldsb[r * 132 + d] = (bf16)v.x; ldsb[r * 132 + d + 1] = (bf16)v.y;
            ldsb[r * 132 + d + 2] = (bf16)v.z; ldsb[r * 132 + d + 3] = (bf16)v.w;
            s1 += v.x * w4Q[d] + v.y * w4Q[d + 1] + v.z * w4Q[d + 2] + v.w * w4Q[d + 3];
        }
        s1 += __shfl_xor(s1, 1);
        s1 += __shfl_xor(s1, 2);
        if ((t & 3) == 0) sub1[b * LQ + q0 + r] = s1;
        __syncthreads();

#pragma unroll
        for (int p = 0; p < 4; ++p) {
            int idx = p * 256 + t;
            int chunk = idx >> 6, w = idx & 63;
            int qb_l = chunk >> 2, ks = chunk & 3;
            int lr = w & 15, lg = w >> 4;
            bf16x8 v = *(bf16x8*)&ldsb[(qb_l * 16 + lr) * 132 + ks * 32 + lg * 8];
            size_t off = ((size_t)((b * 16 + qt * 4 + qb_l) * 4 + ks)) * 512 + w * 8;
            *(bf16x8*)(Qbp + off) = v;
        }
#pragma unroll
        for (int p = 0; p < 4; ++p) {
            int idx = p * 256 + t;
            int chunk = idx >> 6, w = idx & 63;
            int ks_l = chunk >> 3, dt = chunk & 7;
            int lr = w & 15, lg = w >> 4;
            int d = dt * 16 + lr, ql = ks_l * 32 + lg * 8;
            bf16x8 v;
#pragma unroll
            for (int j = 0; j < 8; ++j) v[j] = ldsb[(ql + j) * 132 + d];
            size_t off = ((size_t)((b * 8 + qt * 2 + ks_l) * 8 + dt)) * 512 + w * 8;
            *(bf16x8*)(QbTp + off) = v;
        }
    }
}

// ---------------------------------------------------------------------------
// K2: S = Cw@Qb^T + subs + bias; P = Qm*exp(S-8) -> Pp only;
//     Rpart rowsum partials, Lpart masked colsum partials.
// grid 4096 1D (XCD-swizzled); block 128c x 64q; LDS 20.5 KB
// ---------------------------------------------------------------------------
__global__ __launch_bounds__(256) void k_s(const bf16* __restrict__ Cwp,
    const bf16* __restrict__ Qbp, const float* __restrict__ sub0,
    const float* __restrict__ sub1, const float* __restrict__ Qmask,
    const float* __restrict__ Cmask, const float* __restrict__ bias,
    bf16* __restrict__ Pp, float* __restrict__ Rpart, float* __restrict__ Lpart)
{
    __shared__ bf16 ldsP[128][80];    // [c_local][q_local]
    int id = blockIdx.x;
    int xcd = id & 7, slot = id >> 3;            // same-b -> same XCD
    int b = xcd * 8 + (slot >> 6);
    int rem = slot & 63;
    int ctile = rem >> 2, qt = rem & 3;
    int q0 = qt * 64;
    int t = threadIdx.x, wid = t >> 6, lane = t & 63;
    int lr = lane & 15, lg = lane >> 4;
    int rowbase = ctile * 128 + wid * 32;

    f32x4 acc[2][4];
#pragma unroll
    for (int rt = 0; rt < 2; ++rt)
#pragma unroll
        for (int ct = 0; ct < 4; ++ct) acc[rt][ct] = (f32x4){0.f, 0.f, 0.f, 0.f};

    const bf16* Ab = Cwp + ((size_t)((b * 128 + ctile * 8 + wid * 2) * 4)) * 512 + lane * 8;
    const bf16* Bb = Qbp + ((size_t)((b * 16 + qt * 4) * 4)) * 512 + lane * 8;
#pragma unroll
    for (int ks = 0; ks < 4; ++ks) {
        bf16x8 a0 = *(const bf16x8*)(Ab + (size_t)ks * 512);
        bf16x8 a1 = *(const bf16x8*)(Ab + (size_t)(4 + ks) * 512);
#pragma unroll
        for (int ct = 0; ct < 4; ++ct) {
            bf16x8 bb = *(const bf16x8*)(Bb + (size_t)(ct * 4 + ks) * 512);
            acc[0][ct] = MFMA16(a0, bb, acc[0][ct]);
            acc[1][ct] = MFMA16(a1, bb, acc[1][ct]);
        }
    }

    float biasv = bias[0];
    float sub0v[2][4], cmv[2][4];
#pragma unroll
    for (int rt = 0; rt < 2; ++rt)
#pragma unroll
        for (int j = 0; j < 4; ++j) {
            int idx = b * LC + rowbase + rt * 16 + lg * 4 + j;
            sub0v[rt][j] = sub0[idx];
            cmv[rt][j] = Cmask[idx];
        }

    float rsum[2][4] = {};
#pragma unroll
    for (int ct = 0; ct < 4; ++ct) {
        int q = q0 + ct * 16 + lr;
        float s1v = sub1[b * LQ + q] + biasv;
        float qm = Qmask[b * LQ + q];
        float colsum = 0.f;
#pragma unroll
        for (int rt = 0; rt < 2; ++rt)
#pragma unroll
            for (int j = 0; j < 4; ++j) {
                float S = acc[rt][ct][j] + sub0v[rt][j] + s1v;
                float Pv = __expf(S - 8.0f) * qm;
                rsum[rt][j] += Pv;
                colsum += Pv * cmv[rt][j];
                ldsP[wid * 32 + rt * 16 + lg * 4 + j][ct * 16 + lr] = (bf16)Pv;
            }
        colsum += __shfl_xor(colsum, 16);
        colsum += __shfl_xor(colsum, 32);
        if (lg == 0)
            Lpart[((size_t)(b * 64 + ctile * 4 + wid)) * LQ + q] = colsum;
    }
#pragma unroll
    for (int rt = 0; rt < 2; ++rt)
#pragma unroll
        for (int j = 0; j < 4; ++j) {
            float s = rsum[rt][j];
            s += __shfl_xor(s, 1);
            s += __shfl_xor(s, 2);
            s += __shfl_xor(s, 4);
            s += __shfl_xor(s, 8);
            if (lr == 0)
                Rpart[((size_t)(b * 4 + qt)) * LC + rowbase + rt * 16 + lg * 4 + j] = s;
        }
    __syncthreads();

    // Pp panels: 16 chunks (cb_l 0..7, ks_l 0..1), lane-linear
#pragma unroll
    for (int p = 0; p < 4; ++p) {
        int idx = p * 256 + t;
        int chunk = idx >> 6, w = idx & 63;
        int cb_l = chunk >> 1, ks_l = chunk & 1;
        int plr = w & 15, plg = w >> 4;
        bf16x8 v = *(bf16x8*)&ldsP[cb_l * 16 + plr][ks_l * 32 + plg * 8];
        size_t off = ((size_t)((b * 128 + ctile * 8 + cb_l) * 8 + qt * 2 + ks_l)) * 512 + w * 8;
        *(bf16x8*)(Pp + off) = v;
    }
}

// ---------------------------------------------------------------------------
// K3: 4-way K-split GEMM: MTp slice = sum over 512 c of CbTm[d][c]*P[c][q]
//   B-operand built by transpose-on-ds_write from Pp (stage [q64][c32,pad40]).
// grid 1024 1D (XCD-swizzled); 16 K-steps; double-buffered.
// ---------------------------------------------------------------------------
__global__ __launch_bounds__(256) void k_m(const bf16* __restrict__ CbTmp,
    const bf16* __restrict__ Pp, bf16* __restrict__ MTp)
{
    __shared__ bf16 stage[2][64 * 40];   // 2 x 5120 B
    int id = blockIdx.x;
    int xcd = id & 7, slot = id >> 3;            // same-b -> same XCD
    int b = xcd * 8 + (slot >> 4);
    int rem = slot & 15;
    int qt = rem & 3, ksl = rem >> 2;
    int t = threadIdx.x, wid = t >> 6, lane = t & 63;
    int lr = lane & 15, lg = lane >> 4;
    int dbase = wid * 32;

    f32x4 acc[2][4];
#pragma unroll
    for (int rt = 0; rt < 2; ++rt)
#pragma unroll
        for (int ct = 0; ct < 4; ++ct) acc[rt][ct] = (f32x4){0.f, 0.f, 0.f, 0.f};

    const bf16* Ab = CbTmp + ((size_t)(b * 64 + ksl * 16) * 128 + dbase + lr) * 32 + lg * 8;
    int cb_off = wid & 1, qh = wid >> 1;
    const bf16* Bsrc = Pp + ((size_t)((b * 128 + ksl * 32 + cb_off) * 8) + qt * 2 + qh) * 512
                       + lane * 8;
    int c_local = cb_off * 16 + lr;
    int qrow = qh * 32 + lg * 8;

    {
        bf16x8 g = *(const bf16x8*)(Bsrc);
#pragma unroll
        for (int i = 0; i < 8; ++i) stage[0][(qrow + i) * 40 + c_local] = g[i];
    }
    __syncthreads();

    for (int ks = 0; ks < 16; ++ks) {
        int cur = ks & 1;
        bf16x8 g;
        if (ks < 15) g = *(const bf16x8*)(Bsrc + (size_t)(ks + 1) * 8192);
        bf16x8 a0 = *(const bf16x8*)(Ab + (size_t)ks * 4096);
        bf16x8 a1 = *(const bf16x8*)(Ab + (size_t)ks * 4096 + 512);
#pragma unroll
        for (int ct = 0; ct < 4; ++ct) {
            bf16x8 bb = *(bf16x8*)&stage[cur][(ct * 16 + lr) * 40 + lg * 8];
            acc[0][ct] = MFMA16(a0, bb, acc[0][ct]);
            acc[1][ct] = MFMA16(a1, bb, acc[1][ct]);
        }
        if (ks < 15) {
#pragma unroll
            for (int i = 0; i < 8; ++i) stage[cur ^ 1][(qrow + i) * 40 + c_local] = g[i];
        }
        __syncthreads();
    }

    size_t base = ((((size_t)ksl * B_ + b) * 4 + qt) * 4 + wid) * 2048;
#pragma unroll
    for (int rt = 0; rt < 2; ++rt)
#pragma unroll
        for (int ct = 0; ct < 4; ++ct)
#pragma unroll
            for (int j = 0; j < 4; ++j)
                MTp[base + (size_t)(rt * 16 + ct * 4 + j) * 64 + lane] = (bf16)acc[rt][ct][j];
}

// ---------------------------------------------------------------------------
// K4: reduce 4 K-slices + fold Linv -> MTpn (lane-linear chunks)
// grid (4, B), 256 thr
// ---------------------------------------------------------------------------
__global__ __launch_bounds__(256) void k_m2(const bf16* __restrict__ MTp,
    const float* __restrict__ Lpart, bf16* __restrict__ MTpn)
{
    __shared__ float ldsLinv[256];
    int b = blockIdx.y, ih = blockIdx.x;
    int t = threadIdx.x;
    {
        float s = 0.f;
#pragma unroll
        for (int sl = 0; sl < 64; ++sl) s += Lpart[((size_t)(b * 64 + sl)) * LQ + t];
        ldsLinv[t] = 1.0f / fmaxf(s, 1e-30f);
    }
    __syncthreads();
#pragma unroll
    for (int i = 0; i < 4; ++i) {
        int slot = (ih * 4 + i) * 256 + t;    // 0..4095
        int d = slot >> 5, qo = slot & 31;
        int q0 = qo * 8;
        int qt = q0 >> 6, ct = (q0 >> 4) & 3, lr0 = q0 & 15;
        int wid = d >> 5, rt = (d >> 4) & 1, lgd = (d >> 2) & 3, j = d & 3;
        size_t roff = ((size_t)(b * 4 + qt)) * 8192 + wid * 2048
                      + (rt * 16 + ct * 4 + j) * 64 + lgd * 16 + lr0;
        float a8[8] = {0.f, 0.f, 0.f, 0.f, 0.f, 0.f, 0.f, 0.f};
#pragma unroll
        for (int sl = 0; sl < 4; ++sl) {
            bf16x8 x = *(const bf16x8*)(MTp + (size_t)sl * B_ * 32768 + roff);
#pragma unroll
            for (int k = 0; k < 8; ++k) a8[k] += (float)x[k];
        }
        bf16x8 o;
#pragma unroll
        for (int k = 0; k < 8; ++k) o[k] = (bf16)(a8[k] * ldsLinv[q0 + k]);
        size_t woff = ((size_t)((b * 8 + (qo >> 2)) * 8 + (d >> 4))) * 512
                      + ((qo & 3) * 16 + (d & 15)) * 8;
        *(bf16x8*)(MTpn + woff) = o;
    }
}

// ---------------------------------------------------------------------------
// K5: A = Rinv*(P@Qb), Bt = Rinv*(P@M). C from out block 0 (fp32). NT stores.
// grid 2048 1D (XCD-swizzled)
// ---------------------------------------------------------------------------
__global__ __launch_bounds__(256) void k_out(const bf16* __restrict__ Pp,
    const bf16* __restrict__ QbTp, const bf16* __restrict__ MTpn,
    const float* __restrict__ Rpart, float* __restrict__ out)
{
    __shared__ f32x4 smem4[2304];                       // 36864 B
    bf16* stage = (bf16*)smem4;                         // stage[2][8192] (32 KB)
    bf16 (*ldsA)[72] = (bf16(*)[72])smem4;              // epilogue-only (union)
    bf16 (*ldsB)[72] = (bf16(*)[72])((char*)smem4 + 18432);

    int id = blockIdx.x;
    int xcd = id & 7, slot = id >> 3;            // same-b -> same XCD
    int b = xcd * 8 + (slot >> 5);
    int ctile = slot & 31;
    int t = threadIdx.x, wid = t >> 6, lane = t & 63;
    int lr = lane & 15, lg = lane >> 4;
    int c0 = ctile * 64;

    const bf16* gsrc = (wid < 2 ? QbTp : MTpn) + (size_t)b * 32768
                       + (size_t)(wid & 1) * 2048 + lane * 8;
    int ldst = wid * 2048 + lane * 8;

    f32x4 rs = (f32x4){0.f, 0.f, 0.f, 0.f};
#pragma unroll
    for (int s = 0; s < 4; ++s)
        rs += *(const f32x4*)(Rpart + ((size_t)(b * 4 + s)) * LC + c0 + wid * 16 + lg * 4);
    f32x4 rv;
#pragma unroll
    for (int j = 0; j < 4; ++j) rv[j] = 1.0f / fmaxf(rs[j], 1e-30f);

    f32x4 accA[8], accB[8];
#pragma unroll
    for (int dt = 0; dt < 8; ++dt) {
        accA[dt] = (f32x4){0.f, 0.f, 0.f, 0.f};
        accB[dt] = (f32x4){0.f, 0.f, 0.f, 0.f};
    }
    const bf16* Ab = Pp + ((size_t)((b * 128 + ctile * 4 + wid) * 8)) * 512 + lane * 8;

    {
        bf16x8 g0 = *(const bf16x8*)(gsrc);
        bf16x8 g1 = *(const bf16x8*)(gsrc + 512);
        bf16x8 g2 = *(const bf16x8*)(gsrc + 1024);
        bf16x8 g3 = *(const bf16x8*)(gsrc + 1536);
        *(bf16x8*)&stage[ldst]        = g0;
        *(bf16x8*)&stage[ldst + 512]  = g1;
        *(bf16x8*)&stage[ldst + 1024] = g2;
        *(bf16x8*)&stage[ldst + 1536] = g3;
    }
    __syncthreads();

    for (int ks = 0; ks < 8; ++ks) {
        int cur = (ks & 1) * 8192;
        bf16x8 g0, g1, g2, g3;
        if (ks < 7) {
            const bf16* gs = gsrc + (size_t)(ks + 1) * 4096;
            g0 = *(const bf16x8*)(gs);
            g1 = *(const bf16x8*)(gs + 512);
            g2 = *(const bf16x8*)(gs + 1024);
            g3 = *(const bf16x8*)(gs + 1536);
        }
        bf16x8 a = *(const bf16x8*)(Ab + (size_t)ks * 512);
        int foff = cur + lane * 8;
#pragma unroll
        for (int dt = 0; dt < 8; ++dt) {
            bf16x8 bq = *(bf16x8*)&stage[foff + dt * 512];
            bf16x8 bm = *(bf16x8*)&stage[foff + 4096 + dt * 512];
            accA[dt] = MFMA16(a, bq, accA[dt]);
            accB[dt] = MFMA16(a, bm, accB[dt]);
        }
        if (ks < 7) {
            int nb = cur ^ 8192;
            *(bf16x8*)&stage[nb + ldst]        = g0;
            *(bf16x8*)&stage[nb + ldst + 512]  = g1;
            *(bf16x8*)&stage[nb + ldst + 1024] = g2;
            *(bf16x8*)&stage[nb + ldst + 1536] = g3;
        }
        __syncthreads();
    }

#pragma unroll
    for (int dt = 0; dt < 8; ++dt) {
        f32x4 a4 = accA[dt] * rv;
        f32x4 b4 = accB[dt] * rv;
        bf16x4 pa = { (bf16)a4[0], (bf16)a4[1], (bf16)a4[2], (bf16)a4[3] };
        bf16x4 pb = { (bf16)b4[0], (bf16)b4[1], (bf16)b4[2], (bf16)b4[3] };
        *(bf16x4*)&ldsA[dt * 16 + lr][wid * 16 + lg * 4] = pa;
        *(bf16x4*)&ldsB[dt * 16 + lr][wid * 16 + lg * 4] = pb;
    }
    __syncthreads();

    float* obase = out + ((size_t)b * 512) * LC;
#pragma unroll
    for (int pass = 0; pass < 8; ++pass) {
        int d = pass * 16 + (t >> 4);
        int cq = (t & 15) * 4;
        bf16x4 av = *(bf16x4*)&ldsA[d][cq];
        bf16x4 bv = *(bf16x4*)&ldsB[d][cq];
        f32x4 c4 = *(const f32x4*)(obase + (size_t)d * LC + c0 + cq);
        f32x4 a4 = {(float)av[0], (float)av[1], (float)av[2], (float)av[3]};
        f32x4 b4 = {(float)bv[0], (float)bv[1], (float)bv[2], (float)bv[3]};
        __builtin_nontemporal_store(a4, (f32x4*)(obase + (size_t)(128 + d) * LC + c0 + cq));
        __builtin_nontemporal_store(c4 * a4, (f32x4*)(obase + (size_t)(256 + d) * LC + c0 + cq));
        __builtin_nontemporal_store(c4 * b4, (f32x4*)(obase + (size_t)(384 + d) * LC + c0 + cq));
    }
}

// ---------------------------------------------------------------------------
extern "C" void kernel_launch(void* const* d_in, const int* in_sizes, int n_in,
                              void* d_out, int out_size, void* d_ws, size_t ws_size,
                              hipStream_t stream)
{
    const float* C     = (const float*)d_in[0];
    const float* Q     = (const float*)d_in[1];
    const float* Cmask = (const float*)d_in[2];
    const float* Qmask = (const float*)d_in[3];
    const float* w4C   = (const float*)d_in[4];
    const float* w4Q   = (const float*)d_in[5];
    const float* w4mlu = (const float*)d_in[6];
    const float* bias  = (const float*)d_in[7];
    float* out = (float*)d_out;

    char* ws = (char*)d_ws;
    size_t off = 0;
    auto alloc = [&](size_t bytes) -> char* {
        char* p = ws + off;
        off += (bytes + 255) & ~(size_t)255;
        return p;
    };
    bf16* Cwp   = (bf16*)alloc((size_t)B_ * LC * DD * 2);
    bf16* CbTmp = (bf16*)alloc((size_t)B_ * LC * DD * 2);
    bf16* Qbp   = (bf16*)alloc((size_t)B_ * LQ * DD * 2);
    bf16* QbTp  = (bf16*)alloc((size_t)B_ * LQ * DD * 2);
    bf16* Pp    = (bf16*)alloc((size_t)B_ * LC * LQ * 2);
    bf16* MTp   = (bf16*)alloc((size_t)4 * B_ * DD * LQ * 2);
    bf16* MTpn  = (bf16*)alloc((size_t)B_ * DD * LQ * 2);
    float* sub0 = (float*)alloc((size_t)B_ * LC * 4);
    float* sub1 = (float*)alloc((size_t)B_ * LQ * 4);
    float* Rpart = (float*)alloc((size_t)B_ * 4 * LC * 4);
    float* Lpart = (float*)alloc((size_t)B_ * 64 * LQ * 4);
    (void)ws_size; (void)in_sizes; (void)n_in; (void)out_size;

    hipLaunchKernelGGL(k_prep, dim3(2304), dim3(256), 0, stream,
                       C, Q, Cmask, w4C, w4Q, w4mlu, Cwp, CbTmp, Qbp, QbTp, sub0, sub1, out);
    hipLaunchKernelGGL(k_s, dim3(4096), dim3(256), 0, stream,
                       Cwp, Qbp, sub0, sub1, Qmask, Cmask, bias, Pp, Rpart, Lpart);
    hipLaunchKernelGGL(k_m, dim3(1024), dim3(256), 0, stream, CbTmp, Pp, MTp);
    hipLaunchKernelGGL(k_m2, dim3(4, B_), dim3(256), 0, stream, MTp, Lpart, MTpn);
    hipLaunchKernelGGL(k_out, dim3(2048), dim3(256), 0, stream,
                       Pp, QbTp, MTpn, Rpart, out);
}

// Round 14
// 169.675 us; speedup vs baseline: 1.2976x; 1.1700x over previous
//
#include <hip/hip_runtime.h>

#define B_ 64
#define LC 2048
#define LQ 256
#define DD 128

typedef __bf16 bf16;
typedef __bf16 bf16x8 __attribute__((ext_vector_type(8)));
typedef __bf16 bf16x4 __attribute__((ext_vector_type(4)));
typedef float f32x4 __attribute__((ext_vector_type(4)));

#define MFMA16(a, b, c) __builtin_amdgcn_mfma_f32_16x16x32_bf16((a), (b), (c), 0, 0, 0)

// Panel layouts (bf16, chunk = 512 elems = 1KB), within-chunk LANE-LINEAR:
// fragment for MFMA-lane l sits at elems [l*8 .. l*8+7].
//  Cwp   [b][cb  (LC/16)][ks 4 ][512]  frag(lr,lg): c=cb*16+lr, d=ks*32+lg*8+i  (*w4mlu)
//  Qbp   [b][qb  (LQ/16)][ks 4 ][512]  frag(lr,lg): q=qb*16+lr, d=ks*32+lg*8+i
//  QbTp  [b][ks  (LQ/32)][dt 8 ][512]  frag(lr,lg): d=dt*16+lr, q=ks*32+lg*8+i
//  CbTp  [b][cb32(LC/32)][d 128][32 ]  elem (c=cb32*32+ci, d) = bf16(C)^T  (UNmasked;
//        Cmask applied in-register in k_m; k_out reads it for C*A / C*Bt)
//  Pp    [b][cb  (LC/16)][ks 8 ][512]  frag(lr,lg): c=cb*16+lr, q=ks*32+lg*8+i (UNmasked)
//  MTpn  [b][ks 8][dt 8][512]          frag(lr,lg): d=dt*16+lr, q=ks*32+lg*8+i (Linv folded)
// XCD swizzle (k_s/k_m/k_out): 1-D grid, xcd = id&7, same-b blocks co-located.
// NT loads on single-reader streams (Pp, MTp) preserve L2 for shared panels.

// ---------------------------------------------------------------------------
// K1 (merged preps): blocks 0..2047 = C path; 2048..2303 = Q path.
// ---------------------------------------------------------------------------
__global__ __launch_bounds__(256) void k_prep(const float* __restrict__ C,
    const float* __restrict__ Q, const float* __restrict__ w4C,
    const float* __restrict__ w4Q, const float* __restrict__ w4mlu,
    bf16* __restrict__ Cwp, bf16* __restrict__ CbTp,
    bf16* __restrict__ Qbp, bf16* __restrict__ QbTp,
    float* __restrict__ sub0, float* __restrict__ sub1, float* __restrict__ out)
{
    __shared__ float lds[64][DD + 4];
    int t = threadIdx.x;
    if (blockIdx.x < 2048) {
        int b = blockIdx.x >> 5, ct = blockIdx.x & 31;
        int c0 = ct * 64;
        int r = t >> 2, cb = (t & 3) * 32;
        size_t rowoff = ((size_t)(b * LC + c0 + r)) * DD + cb;
        const float4* src = (const float4*)(C + rowoff);
        float s0 = 0.f;
#pragma unroll
        for (int i = 0; i < 8; ++i) {
            float4 v = src[i];
            int d = cb + i * 4;
            lds[r][d] = v.x; lds[r][d + 1] = v.y; lds[r][d + 2] = v.z; lds[r][d + 3] = v.w;
            s0 += v.x * w4C[d] + v.y * w4C[d + 1] + v.z * w4C[d + 2] + v.w * w4C[d + 3];
        }
        s0 += __shfl_xor(s0, 1);
        s0 += __shfl_xor(s0, 2);
        if ((t & 3) == 0) sub0[b * LC + c0 + r] = s0;
        __syncthreads();

#pragma unroll
        for (int p = 0; p < 4; ++p) {
            int idx = p * 256 + t;
            int chunk = idx >> 6, w = idx & 63;
            int cb_l = chunk >> 2, ks = chunk & 3;
            int lr = w & 15, lg = w >> 4;
            int c_l = cb_l * 16 + lr, d0 = ks * 32 + lg * 8;
            bf16x8 v;
#pragma unroll
            for (int j = 0; j < 8; ++j) v[j] = (bf16)(lds[c_l][d0 + j] * w4mlu[d0 + j]);
            size_t off = ((size_t)((b * 128 + ct * 4 + cb_l) * 4 + ks)) * 512 + w * 8;
            *(bf16x8*)(Cwp + off) = v;
        }
        // CbTp panels (UNmasked)
#pragma unroll
        for (int p = 0; p < 4; ++p) {
            int idx = p * 256 + t;
            int cb32 = idx >> 9, rem = idx & 511;
            int d = rem >> 2, lg = rem & 3;
            int cl0 = cb32 * 32 + lg * 8;
            bf16x8 v;
#pragma unroll
            for (int j = 0; j < 8; ++j) v[j] = (bf16)lds[cl0 + j][d];
            size_t off = ((size_t)((b * 64 + ct * 2 + cb32) * 128 + d)) * 32 + lg * 8;
            *(bf16x8*)(CbTp + off) = v;
        }
        // out block 0: exact fp32 C^T, NT stores (never re-read)
#pragma unroll
        for (int p = 0; p < 8; ++p) {
            int d = p * 16 + (t >> 4);
            int cl = (t & 15) * 4;
            f32x4 v = {lds[cl][d], lds[cl + 1][d], lds[cl + 2][d], lds[cl + 3][d]};
            __builtin_nontemporal_store(v,
                (f32x4*)(out + ((size_t)(b * 512 + d)) * LC + c0 + cl));
        }
    } else {
        int idx0 = blockIdx.x - 2048;
        int b = idx0 >> 2, qt = idx0 & 3;
        int q0 = qt * 64;
        bf16* ldsb = (bf16*)lds;   // reuse as bf16 [64][132]
        int r = t >> 2, cb = (t & 3) * 32;
        size_t rowoff = ((size_t)(b * LQ + q0 + r)) * DD + cb;
        const float4* src = (const float4*)(Q + rowoff);
        float s1 = 0.f;
#pragma unroll
        for (int i = 0; i < 8; ++i) {
            float4 v = src[i];
            int d = cb + i * 4;
            ldsb[r * 132 + d] = (bf16)v.x; ldsb[r * 132 + d + 1] = (bf16)v.y;
            ldsb[r * 132 + d + 2] = (bf16)v.z; ldsb[r * 132 + d + 3] = (bf16)v.w;
            s1 += v.x * w4Q[d] + v.y * w4Q[d + 1] + v.z * w4Q[d + 2] + v.w * w4Q[d + 3];
        }
        s1 += __shfl_xor(s1, 1);
        s1 += __shfl_xor(s1, 2);
        if ((t & 3) == 0) sub1[b * LQ + q0 + r] = s1;
        __syncthreads();

#pragma unroll
        for (int p = 0; p < 4; ++p) {
            int idx = p * 256 + t;
            int chunk = idx >> 6, w = idx & 63;
            int qb_l = chunk >> 2, ks = chunk & 3;
            int lr = w & 15, lg = w >> 4;
            bf16x8 v = *(bf16x8*)&ldsb[(qb_l * 16 + lr) * 132 + ks * 32 + lg * 8];
            size_t off = ((size_t)((b * 16 + qt * 4 + qb_l) * 4 + ks)) * 512 + w * 8;
            *(bf16x8*)(Qbp + off) = v;
        }
#pragma unroll
        for (int p = 0; p < 4; ++p) {
            int idx = p * 256 + t;
            int chunk = idx >> 6, w = idx & 63;
            int ks_l = chunk >> 3, dt = chunk & 7;
            int lr = w & 15, lg = w >> 4;
            int d = dt * 16 + lr, ql = ks_l * 32 + lg * 8;
            bf16x8 v;
#pragma unroll
            for (int j = 0; j < 8; ++j) v[j] = ldsb[(ql + j) * 132 + d];
            size_t off = ((size_t)((b * 8 + qt * 2 + ks_l) * 8 + dt)) * 512 + w * 8;
            *(bf16x8*)(QbTp + off) = v;
        }
    }
}

// ---------------------------------------------------------------------------
// K2: S = Cw@Qb^T + subs + bias; P = Qm*exp(S-8) -> Pp only;
//     Rpart rowsum partials, Lpart masked colsum partials.
// grid 4096 1D (XCD-swizzled); block 128c x 64q; LDS 20.5 KB
// ---------------------------------------------------------------------------
__global__ __launch_bounds__(256) void k_s(const bf16* __restrict__ Cwp,
    const bf16* __restrict__ Qbp, const float* __restrict__ sub0,
    const float* __restrict__ sub1, const float* __restrict__ Qmask,
    const float* __restrict__ Cmask, const float* __restrict__ bias,
    bf16* __restrict__ Pp, float* __restrict__ Rpart, float* __restrict__ Lpart)
{
    __shared__ bf16 ldsP[128][80];    // [c_local][q_local]
    int id = blockIdx.x;
    int xcd = id & 7, slot = id >> 3;            // same-b -> same XCD
    int b = xcd * 8 + (slot >> 6);
    int rem = slot & 63;
    int ctile = rem >> 2, qt = rem & 3;
    int q0 = qt * 64;
    int t = threadIdx.x, wid = t >> 6, lane = t & 63;
    int lr = lane & 15, lg = lane >> 4;
    int rowbase = ctile * 128 + wid * 32;

    f32x4 acc[2][4];
#pragma unroll
    for (int rt = 0; rt < 2; ++rt)
#pragma unroll
        for (int ct = 0; ct < 4; ++ct) acc[rt][ct] = (f32x4){0.f, 0.f, 0.f, 0.f};

    const bf16* Ab = Cwp + ((size_t)((b * 128 + ctile * 8 + wid * 2) * 4)) * 512 + lane * 8;
    const bf16* Bb = Qbp + ((size_t)((b * 16 + qt * 4) * 4)) * 512 + lane * 8;
#pragma unroll
    for (int ks = 0; ks < 4; ++ks) {
        bf16x8 a0 = *(const bf16x8*)(Ab + (size_t)ks * 512);
        bf16x8 a1 = *(const bf16x8*)(Ab + (size_t)(4 + ks) * 512);
#pragma unroll
        for (int ct = 0; ct < 4; ++ct) {
            bf16x8 bb = *(const bf16x8*)(Bb + (size_t)(ct * 4 + ks) * 512);
            acc[0][ct] = MFMA16(a0, bb, acc[0][ct]);
            acc[1][ct] = MFMA16(a1, bb, acc[1][ct]);
        }
    }

    float biasv = bias[0];
    float sub0v[2][4], cmv[2][4];
#pragma unroll
    for (int rt = 0; rt < 2; ++rt)
#pragma unroll
        for (int j = 0; j < 4; ++j) {
            int idx = b * LC + rowbase + rt * 16 + lg * 4 + j;
            sub0v[rt][j] = sub0[idx];
            cmv[rt][j] = Cmask[idx];
        }

    float rsum[2][4] = {};
#pragma unroll
    for (int ct = 0; ct < 4; ++ct) {
        int q = q0 + ct * 16 + lr;
        float s1v = sub1[b * LQ + q] + biasv;
        float qm = Qmask[b * LQ + q];
        float colsum = 0.f;
#pragma unroll
        for (int rt = 0; rt < 2; ++rt)
#pragma unroll
            for (int j = 0; j < 4; ++j) {
                float S = acc[rt][ct][j] + sub0v[rt][j] + s1v;
                float Pv = __expf(S - 8.0f) * qm;
                rsum[rt][j] += Pv;
                colsum += Pv * cmv[rt][j];
                ldsP[wid * 32 + rt * 16 + lg * 4 + j][ct * 16 + lr] = (bf16)Pv;
            }
        colsum += __shfl_xor(colsum, 16);
        colsum += __shfl_xor(colsum, 32);
        if (lg == 0)
            Lpart[((size_t)(b * 64 + ctile * 4 + wid)) * LQ + q] = colsum;
    }
#pragma unroll
    for (int rt = 0; rt < 2; ++rt)
#pragma unroll
        for (int j = 0; j < 4; ++j) {
            float s = rsum[rt][j];
            s += __shfl_xor(s, 1);
            s += __shfl_xor(s, 2);
            s += __shfl_xor(s, 4);
            s += __shfl_xor(s, 8);
            if (lr == 0)
                Rpart[((size_t)(b * 4 + qt)) * LC + rowbase + rt * 16 + lg * 4 + j] = s;
        }
    __syncthreads();

    // Pp panels: 16 chunks (cb_l 0..7, ks_l 0..1), lane-linear
#pragma unroll
    for (int p = 0; p < 4; ++p) {
        int idx = p * 256 + t;
        int chunk = idx >> 6, w = idx & 63;
        int cb_l = chunk >> 1, ks_l = chunk & 1;
        int plr = w & 15, plg = w >> 4;
        bf16x8 v = *(bf16x8*)&ldsP[cb_l * 16 + plr][ks_l * 32 + plg * 8];
        size_t off = ((size_t)((b * 128 + ctile * 8 + cb_l) * 8 + qt * 2 + ks_l)) * 512 + w * 8;
        *(bf16x8*)(Pp + off) = v;
    }
}

// ---------------------------------------------------------------------------
// K3: 4-way K-split GEMM: MTp slice = sum over 512 c of (CbT*Cmask)[d][c]*P[c][q]
//   Cmask applied in-register to A-fragments (broadcast loads; exact 0/1).
//   B-operand via transpose-on-ds_write from Pp (NT loads).
// grid 1024 1D (XCD-swizzled); 16 K-steps; double-buffered.
// ---------------------------------------------------------------------------
__global__ __launch_bounds__(256) void k_m(const bf16* __restrict__ CbTp,
    const bf16* __restrict__ Pp, const float* __restrict__ Cmask,
    bf16* __restrict__ MTp)
{
    __shared__ bf16 stage[2][64 * 40];   // 2 x 5120 B
    int id = blockIdx.x;
    int xcd = id & 7, slot = id >> 3;            // same-b -> same XCD
    int b = xcd * 8 + (slot >> 4);
    int rem = slot & 15;
    int qt = rem & 3, ksl = rem >> 2;
    int t = threadIdx.x, wid = t >> 6, lane = t & 63;
    int lr = lane & 15, lg = lane >> 4;
    int dbase = wid * 32;

    f32x4 acc[2][4];
#pragma unroll
    for (int rt = 0; rt < 2; ++rt)
#pragma unroll
        for (int ct = 0; ct < 4; ++ct) acc[rt][ct] = (f32x4){0.f, 0.f, 0.f, 0.f};

    const bf16* Ab = CbTp + ((size_t)(b * 64 + ksl * 16) * 128 + dbase + lr) * 32 + lg * 8;
    const float* Mb = Cmask + b * LC + ksl * 512 + lg * 8;
    int cb_off = wid & 1, qh = wid >> 1;
    const bf16* Bsrc = Pp + ((size_t)((b * 128 + ksl * 32 + cb_off) * 8) + qt * 2 + qh) * 512
                       + lane * 8;
    int c_local = cb_off * 16 + lr;
    int qrow = qh * 32 + lg * 8;

    {
        bf16x8 g = __builtin_nontemporal_load((const bf16x8*)Bsrc);
#pragma unroll
        for (int i = 0; i < 8; ++i) stage[0][(qrow + i) * 40 + c_local] = g[i];
    }
    __syncthreads();

    for (int ks = 0; ks < 16; ++ks) {
        int cur = ks & 1;
        bf16x8 g;
        if (ks < 15) g = __builtin_nontemporal_load((const bf16x8*)(Bsrc + (size_t)(ks + 1) * 8192));
        bf16x8 a0 = *(const bf16x8*)(Ab + (size_t)ks * 4096);
        bf16x8 a1 = *(const bf16x8*)(Ab + (size_t)ks * 4096 + 512);
        // apply Cmask (0/1) to A-fragments: c = ksl*512 + ks*32 + lg*8 + i
        f32x4 m0 = *(const f32x4*)(Mb + ks * 32);
        f32x4 m1 = *(const f32x4*)(Mb + ks * 32 + 4);
        bf16x8 msk;
#pragma unroll
        for (int i = 0; i < 4; ++i) { msk[i] = (bf16)m0[i]; msk[4 + i] = (bf16)m1[i]; }
        a0 = a0 * msk;
        a1 = a1 * msk;
#pragma unroll
        for (int ct = 0; ct < 4; ++ct) {
            bf16x8 bb = *(bf16x8*)&stage[cur][(ct * 16 + lr) * 40 + lg * 8];
            acc[0][ct] = MFMA16(a0, bb, acc[0][ct]);
            acc[1][ct] = MFMA16(a1, bb, acc[1][ct]);
        }
        if (ks < 15) {
#pragma unroll
            for (int i = 0; i < 8; ++i) stage[cur ^ 1][(qrow + i) * 40 + c_local] = g[i];
        }
        __syncthreads();
    }

    size_t base = ((((size_t)ksl * B_ + b) * 4 + qt) * 4 + wid) * 2048;
#pragma unroll
    for (int rt = 0; rt < 2; ++rt)
#pragma unroll
        for (int ct = 0; ct < 4; ++ct)
#pragma unroll
            for (int j = 0; j < 4; ++j)
                MTp[base + (size_t)(rt * 16 + ct * 4 + j) * 64 + lane] = (bf16)acc[rt][ct][j];
}

// ---------------------------------------------------------------------------
// K4: reduce 4 K-slices + fold Linv -> MTpn (lane-linear chunks); NT slice reads
// grid (4, B), 256 thr
// ---------------------------------------------------------------------------
__global__ __launch_bounds__(256) void k_m2(const bf16* __restrict__ MTp,
    const float* __restrict__ Lpart, bf16* __restrict__ MTpn)
{
    __shared__ float ldsLinv[256];
    int b = blockIdx.y, ih = blockIdx.x;
    int t = threadIdx.x;
    {
        float s = 0.f;
#pragma unroll
        for (int sl = 0; sl < 64; ++sl) s += Lpart[((size_t)(b * 64 + sl)) * LQ + t];
        ldsLinv[t] = 1.0f / fmaxf(s, 1e-30f);
    }
    __syncthreads();
#pragma unroll
    for (int i = 0; i < 4; ++i) {
        int slot = (ih * 4 + i) * 256 + t;    // 0..4095
        int d = slot >> 5, qo = slot & 31;
        int q0 = qo * 8;
        int qt = q0 >> 6, ct = (q0 >> 4) & 3, lr0 = q0 & 15;
        int wid = d >> 5, rt = (d >> 4) & 1, lgd = (d >> 2) & 3, j = d & 3;
        size_t roff = ((size_t)(b * 4 + qt)) * 8192 + wid * 2048
                      + (rt * 16 + ct * 4 + j) * 64 + lgd * 16 + lr0;
        float a8[8] = {0.f, 0.f, 0.f, 0.f, 0.f, 0.f, 0.f, 0.f};
#pragma unroll
        for (int sl = 0; sl < 4; ++sl) {
            bf16x8 x = __builtin_nontemporal_load(
                (const bf16x8*)(MTp + (size_t)sl * B_ * 32768 + roff));
#pragma unroll
            for (int k = 0; k < 8; ++k) a8[k] += (float)x[k];
        }
        bf16x8 o;
#pragma unroll
        for (int k = 0; k < 8; ++k) o[k] = (bf16)(a8[k] * ldsLinv[q0 + k]);
        size_t woff = ((size_t)((b * 8 + (qo >> 2)) * 8 + (d >> 4))) * 512
                      + ((qo & 3) * 16 + (d & 15)) * 8;
        *(bf16x8*)(MTpn + woff) = o;
    }
}

// ---------------------------------------------------------------------------
// K5: A = Rinv*(P@Qb), Bt = Rinv*(P@M). C from CbTp (bf16). NT stores+Pp NT loads.
// grid 2048 1D (XCD-swizzled)
// ---------------------------------------------------------------------------
__global__ __launch_bounds__(256) void k_out(const bf16* __restrict__ Pp,
    const bf16* __restrict__ QbTp, const bf16* __restrict__ MTpn,
    const bf16* __restrict__ CbTp, const float* __restrict__ Rpart,
    float* __restrict__ out)
{
    __shared__ f32x4 smem4[2304];                       // 36864 B
    bf16* stage = (bf16*)smem4;                         // stage[2][8192] (32 KB)
    bf16 (*ldsA)[72] = (bf16(*)[72])smem4;              // epilogue-only (union)
    bf16 (*ldsB)[72] = (bf16(*)[72])((char*)smem4 + 18432);

    int id = blockIdx.x;
    int xcd = id & 7, slot = id >> 3;            // same-b -> same XCD
    int b = xcd * 8 + (slot >> 5);
    int ctile = slot & 31;
    int t = threadIdx.x, wid = t >> 6, lane = t & 63;
    int lr = lane & 15, lg = lane >> 4;
    int c0 = ctile * 64;

    const bf16* gsrc = (wid < 2 ? QbTp : MTpn) + (size_t)b * 32768
                       + (size_t)(wid & 1) * 2048 + lane * 8;
    int ldst = wid * 2048 + lane * 8;

    f32x4 rs = (f32x4){0.f, 0.f, 0.f, 0.f};
#pragma unroll
    for (int s = 0; s < 4; ++s)
        rs += *(const f32x4*)(Rpart + ((size_t)(b * 4 + s)) * LC + c0 + wid * 16 + lg * 4);
    f32x4 rv;
#pragma unroll
    for (int j = 0; j < 4; ++j) rv[j] = 1.0f / fmaxf(rs[j], 1e-30f);

    f32x4 accA[8], accB[8];
#pragma unroll
    for (int dt = 0; dt < 8; ++dt) {
        accA[dt] = (f32x4){0.f, 0.f, 0.f, 0.f};
        accB[dt] = (f32x4){0.f, 0.f, 0.f, 0.f};
    }
    const bf16* Ab = Pp + ((size_t)((b * 128 + ctile * 4 + wid) * 8)) * 512 + lane * 8;

    {
        bf16x8 g0 = *(const bf16x8*)(gsrc);
        bf16x8 g1 = *(const bf16x8*)(gsrc + 512);
        bf16x8 g2 = *(const bf16x8*)(gsrc + 1024);
        bf16x8 g3 = *(const bf16x8*)(gsrc + 1536);
        *(bf16x8*)&stage[ldst]        = g0;
        *(bf16x8*)&stage[ldst + 512]  = g1;
        *(bf16x8*)&stage[ldst + 1024] = g2;
        *(bf16x8*)&stage[ldst + 1536] = g3;
    }
    __syncthreads();

    for (int ks = 0; ks < 8; ++ks) {
        int cur = (ks & 1) * 8192;
        bf16x8 g0, g1, g2, g3;
        if (ks < 7) {
            const bf16* gs = gsrc + (size_t)(ks + 1) * 4096;
            g0 = *(const bf16x8*)(gs);
            g1 = *(const bf16x8*)(gs + 512);
            g2 = *(const bf16x8*)(gs + 1024);
            g3 = *(const bf16x8*)(gs + 1536);
        }
        bf16x8 a = __builtin_nontemporal_load((const bf16x8*)(Ab + (size_t)ks * 512));
        int foff = cur + lane * 8;
#pragma unroll
        for (int dt = 0; dt < 8; ++dt) {
            bf16x8 bq = *(bf16x8*)&stage[foff + dt * 512];
            bf16x8 bm = *(bf16x8*)&stage[foff + 4096 + dt * 512];
            accA[dt] = MFMA16(a, bq, accA[dt]);
            accB[dt] = MFMA16(a, bm, accB[dt]);
        }
        if (ks < 7) {
            int nb = cur ^ 8192;
            *(bf16x8*)&stage[nb + ldst]        = g0;
            *(bf16x8*)&stage[nb + ldst + 512]  = g1;
            *(bf16x8*)&stage[nb + ldst + 1024] = g2;
            *(bf16x8*)&stage[nb + ldst + 1536] = g3;
        }
        __syncthreads();
    }

#pragma unroll
    for (int dt = 0; dt < 8; ++dt) {
        f32x4 a4 = accA[dt] * rv;
        f32x4 b4 = accB[dt] * rv;
        bf16x4 pa = { (bf16)a4[0], (bf16)a4[1], (bf16)a4[2], (bf16)a4[3] };
        bf16x4 pb = { (bf16)b4[0], (bf16)b4[1], (bf16)b4[2], (bf16)b4[3] };
        *(bf16x4*)&ldsA[dt * 16 + lr][wid * 16 + lg * 4] = pa;
        *(bf16x4*)&ldsB[dt * 16 + lr][wid * 16 + lg * 4] = pb;
    }
    __syncthreads();

    float* obase = out + ((size_t)b * 512) * LC;
#pragma unroll
    for (int pass = 0; pass < 8; ++pass) {
        int d = pass * 16 + (t >> 4);
        int cq = (t & 15) * 4;
        int cglob = c0 + cq;
        int cb32 = cglob >> 5, ci = cglob & 31;
        bf16x4 av = *(bf16x4*)&ldsA[d][cq];
        bf16x4 bv = *(bf16x4*)&ldsB[d][cq];
        bf16x4 cb4 = *(const bf16x4*)(CbTp + ((size_t)(b * 64 + cb32) * 128 + d) * 32 + ci);
        f32x4 c4 = {(float)cb4[0], (float)cb4[1], (float)cb4[2], (float)cb4[3]};
        f32x4 a4 = {(float)av[0], (float)av[1], (float)av[2], (float)av[3]};
        f32x4 b4 = {(float)bv[0], (float)bv[1], (float)bv[2], (float)bv[3]};
        __builtin_nontemporal_store(a4, (f32x4*)(obase + (size_t)(128 + d) * LC + c0 + cq));
        __builtin_nontemporal_store(c4 * a4, (f32x4*)(obase + (size_t)(256 + d) * LC + c0 + cq));
        __builtin_nontemporal_store(c4 * b4, (f32x4*)(obase + (size_t)(384 + d) * LC + c0 + cq));
    }
}

// ---------------------------------------------------------------------------
extern "C" void kernel_launch(void* const* d_in, const int* in_sizes, int n_in,
                              void* d_out, int out_size, void* d_ws, size_t ws_size,
                              hipStream_t stream)
{
    const float* C     = (const float*)d_in[0];
    const float* Q     = (const float*)d_in[1];
    const float* Cmask = (const float*)d_in[2];
    const float* Qmask = (const float*)d_in[3];
    const float* w4C   = (const float*)d_in[4];
    const float* w4Q   = (const float*)d_in[5];
    const float* w4mlu = (const float*)d_in[6];
    const float* bias  = (const float*)d_in[7];
    float* out = (float*)d_out;

    char* ws = (char*)d_ws;
    size_t off = 0;
    auto alloc = [&](size_t bytes) -> char* {
        char* p = ws + off;
        off += (bytes + 255) & ~(size_t)255;
        return p;
    };
    bf16* Cwp   = (bf16*)alloc((size_t)B_ * LC * DD * 2);
    bf16* CbTp  = (bf16*)alloc((size_t)B_ * LC * DD * 2);
    bf16* Qbp   = (bf16*)alloc((size_t)B_ * LQ * DD * 2);
    bf16* QbTp  = (bf16*)alloc((size_t)B_ * LQ * DD * 2);
    bf16* Pp    = (bf16*)alloc((size_t)B_ * LC * LQ * 2);
    bf16* MTp   = (bf16*)alloc((size_t)4 * B_ * DD * LQ * 2);
    bf16* MTpn  = (bf16*)alloc((size_t)B_ * DD * LQ * 2);
    float* sub0 = (float*)alloc((size_t)B_ * LC * 4);
    float* sub1 = (float*)alloc((size_t)B_ * LQ * 4);
    float* Rpart = (float*)alloc((size_t)B_ * 4 * LC * 4);
    float* Lpart = (float*)alloc((size_t)B_ * 64 * LQ * 4);
    (void)ws_size; (void)in_sizes; (void)n_in; (void)out_size;

    hipLaunchKernelGGL(k_prep, dim3(2304), dim3(256), 0, stream,
                       C, Q, w4C, w4Q, w4mlu, Cwp, CbTp, Qbp, QbTp, sub0, sub1, out);
    hipLaunchKernelGGL(k_s, dim3(4096), dim3(256), 0, stream,
                       Cwp, Qbp, sub0, sub1, Qmask, Cmask, bias, Pp, Rpart, Lpart);
    hipLaunchKernelGGL(k_m, dim3(1024), dim3(256), 0, stream, CbTp, Pp, Cmask, MTp);
    hipLaunchKernelGGL(k_m2, dim3(4, B_), dim3(256), 0, stream, MTp, Lpart, MTpn);
    hipLaunchKernelGGL(k_out, dim3(2048), dim3(256), 0, stream,
                       Pp, QbTp, MTpn, CbTp, Rpart, out);
}

// Round 15
// 156.265 us; speedup vs baseline: 1.4090x; 1.0858x over previous
//
#include <hip/hip_runtime.h>

#define B_ 64
#define LC 2048
#define LQ 256
#define DD 128

typedef __bf16 bf16;
typedef __bf16 bf16x8 __attribute__((ext_vector_type(8)));
typedef __bf16 bf16x4 __attribute__((ext_vector_type(4)));
typedef float f32x4 __attribute__((ext_vector_type(4)));

#define MFMA16(a, b, c) __builtin_amdgcn_mfma_f32_16x16x32_bf16((a), (b), (c), 0, 0, 0)

// Panel layouts (bf16, chunk = 512 elems = 1KB), within-chunk LANE-LINEAR:
// fragment for MFMA-lane l sits at elems [l*8 .. l*8+7].
//  Cwp   [b][cb  (LC/16)][ks 4 ][512]  frag(lr,lg): c=cb*16+lr, d=ks*32+lg*8+i  (*w4mlu)
//  Qbp   [b][qb  (LQ/16)][ks 4 ][512]  frag(lr,lg): q=qb*16+lr, d=ks*32+lg*8+i
//  QbTp  [b][ks  (LQ/32)][dt 8 ][512]  frag(lr,lg): d=dt*16+lr, q=ks*32+lg*8+i
//  CbTp  [b][cb32(LC/32)][d 128][32 ]  elem (c=cb32*32+ci, d) = bf16(C)^T  (UNmasked;
//        Cmask applied in-register in k_m; k_out reads it for C*A / C*Bt)
//  Pp    [b][cb  (LC/16)][ks 8 ][512]  frag(lr,lg): c=cb*16+lr, q=ks*32+lg*8+i (UNmasked)
//  MTpn  [b][ks 8][dt 8][512]          frag(lr,lg): d=dt*16+lr, q=ks*32+lg*8+i (Linv folded)
// XCD swizzle (k_s/k_m/k_out): 1-D grid, xcd = id&7, same-b blocks co-located.
// NT STORES on write-only streams (out); plain loads everywhere (L2/L3 serve
// the producer->consumer streams thanks to XCD co-location).

// ---------------------------------------------------------------------------
// K1 (merged preps): blocks 0..2047 = C path; 2048..2303 = Q path.
// ---------------------------------------------------------------------------
__global__ __launch_bounds__(256) void k_prep(const float* __restrict__ C,
    const float* __restrict__ Q, const float* __restrict__ w4C,
    const float* __restrict__ w4Q, const float* __restrict__ w4mlu,
    bf16* __restrict__ Cwp, bf16* __restrict__ CbTp,
    bf16* __restrict__ Qbp, bf16* __restrict__ QbTp,
    float* __restrict__ sub0, float* __restrict__ sub1, float* __restrict__ out)
{
    __shared__ float lds[64][DD + 4];
    int t = threadIdx.x;
    if (blockIdx.x < 2048) {
        int b = blockIdx.x >> 5, ct = blockIdx.x & 31;
        int c0 = ct * 64;
        int r = t >> 2, cb = (t & 3) * 32;
        size_t rowoff = ((size_t)(b * LC + c0 + r)) * DD + cb;
        const float4* src = (const float4*)(C + rowoff);
        float s0 = 0.f;
#pragma unroll
        for (int i = 0; i < 8; ++i) {
            float4 v = src[i];
            int d = cb + i * 4;
            lds[r][d] = v.x; lds[r][d + 1] = v.y; lds[r][d + 2] = v.z; lds[r][d + 3] = v.w;
            s0 += v.x * w4C[d] + v.y * w4C[d + 1] + v.z * w4C[d + 2] + v.w * w4C[d + 3];
        }
        s0 += __shfl_xor(s0, 1);
        s0 += __shfl_xor(s0, 2);
        if ((t & 3) == 0) sub0[b * LC + c0 + r] = s0;
        __syncthreads();

#pragma unroll
        for (int p = 0; p < 4; ++p) {
            int idx = p * 256 + t;
            int chunk = idx >> 6, w = idx & 63;
            int cb_l = chunk >> 2, ks = chunk & 3;
            int lr = w & 15, lg = w >> 4;
            int c_l = cb_l * 16 + lr, d0 = ks * 32 + lg * 8;
            bf16x8 v;
#pragma unroll
            for (int j = 0; j < 8; ++j) v[j] = (bf16)(lds[c_l][d0 + j] * w4mlu[d0 + j]);
            size_t off = ((size_t)((b * 128 + ct * 4 + cb_l) * 4 + ks)) * 512 + w * 8;
            *(bf16x8*)(Cwp + off) = v;
        }
        // CbTp panels (UNmasked)
#pragma unroll
        for (int p = 0; p < 4; ++p) {
            int idx = p * 256 + t;
            int cb32 = idx >> 9, rem = idx & 511;
            int d = rem >> 2, lg = rem & 3;
            int cl0 = cb32 * 32 + lg * 8;
            bf16x8 v;
#pragma unroll
            for (int j = 0; j < 8; ++j) v[j] = (bf16)lds[cl0 + j][d];
            size_t off = ((size_t)((b * 64 + ct * 2 + cb32) * 128 + d)) * 32 + lg * 8;
            *(bf16x8*)(CbTp + off) = v;
        }
        // out block 0: exact fp32 C^T, NT stores (never re-read)
#pragma unroll
        for (int p = 0; p < 8; ++p) {
            int d = p * 16 + (t >> 4);
            int cl = (t & 15) * 4;
            f32x4 v = {lds[cl][d], lds[cl + 1][d], lds[cl + 2][d], lds[cl + 3][d]};
            __builtin_nontemporal_store(v,
                (f32x4*)(out + ((size_t)(b * 512 + d)) * LC + c0 + cl));
        }
    } else {
        int idx0 = blockIdx.x - 2048;
        int b = idx0 >> 2, qt = idx0 & 3;
        int q0 = qt * 64;
        bf16* ldsb = (bf16*)lds;   // reuse as bf16 [64][132]
        int r = t >> 2, cb = (t & 3) * 32;
        size_t rowoff = ((size_t)(b * LQ + q0 + r)) * DD + cb;
        const float4* src = (const float4*)(Q + rowoff);
        float s1 = 0.f;
#pragma unroll
        for (int i = 0; i < 8; ++i) {
            float4 v = src[i];
            int d = cb + i * 4;
            ldsb[r * 132 + d] = (bf16)v.x; ldsb[r * 132 + d + 1] = (bf16)v.y;
            ldsb[r * 132 + d + 2] = (bf16)v.z; ldsb[r * 132 + d + 3] = (bf16)v.w;
            s1 += v.x * w4Q[d] + v.y * w4Q[d + 1] + v.z * w4Q[d + 2] + v.w * w4Q[d + 3];
        }
        s1 += __shfl_xor(s1, 1);
        s1 += __shfl_xor(s1, 2);
        if ((t & 3) == 0) sub1[b * LQ + q0 + r] = s1;
        __syncthreads();

#pragma unroll
        for (int p = 0; p < 4; ++p) {
            int idx = p * 256 + t;
            int chunk = idx >> 6, w = idx & 63;
            int qb_l = chunk >> 2, ks = chunk & 3;
            int lr = w & 15, lg = w >> 4;
            bf16x8 v = *(bf16x8*)&ldsb[(qb_l * 16 + lr) * 132 + ks * 32 + lg * 8];
            size_t off = ((size_t)((b * 16 + qt * 4 + qb_l) * 4 + ks)) * 512 + w * 8;
            *(bf16x8*)(Qbp + off) = v;
        }
#pragma unroll
        for (int p = 0; p < 4; ++p) {
            int idx = p * 256 + t;
            int chunk = idx >> 6, w = idx & 63;
            int ks_l = chunk >> 3, dt = chunk & 7;
            int lr = w & 15, lg = w >> 4;
            int d = dt * 16 + lr, ql = ks_l * 32 + lg * 8;
            bf16x8 v;
#pragma unroll
            for (int j = 0; j < 8; ++j) v[j] = ldsb[(ql + j) * 132 + d];
            size_t off = ((size_t)((b * 8 + qt * 2 + ks_l) * 8 + dt)) * 512 + w * 8;
            *(bf16x8*)(QbTp + off) = v;
        }
    }
}

// ---------------------------------------------------------------------------
// K2: S = Cw@Qb^T + subs + bias; P = Qm*exp(S-8) -> Pp only;
//     Rpart rowsum partials, Lpart masked colsum partials.
// grid 4096 1D (XCD-swizzled); block 128c x 64q; ldsP pad 82 (conflict-free)
// ---------------------------------------------------------------------------
__global__ __launch_bounds__(256) void k_s(const bf16* __restrict__ Cwp,
    const bf16* __restrict__ Qbp, const float* __restrict__ sub0,
    const float* __restrict__ sub1, const float* __restrict__ Qmask,
    const float* __restrict__ Cmask, const float* __restrict__ bias,
    bf16* __restrict__ Pp, float* __restrict__ Rpart, float* __restrict__ Lpart)
{
    __shared__ bf16 ldsP[128][82];    // [c_local][q_local]; 82 -> 9*lr mod 32 distinct
    int id = blockIdx.x;
    int xcd = id & 7, slot = id >> 3;            // same-b -> same XCD
    int b = xcd * 8 + (slot >> 6);
    int rem = slot & 63;
    int ctile = rem >> 2, qt = rem & 3;
    int q0 = qt * 64;
    int t = threadIdx.x, wid = t >> 6, lane = t & 63;
    int lr = lane & 15, lg = lane >> 4;
    int rowbase = ctile * 128 + wid * 32;

    f32x4 acc[2][4];
#pragma unroll
    for (int rt = 0; rt < 2; ++rt)
#pragma unroll
        for (int ct = 0; ct < 4; ++ct) acc[rt][ct] = (f32x4){0.f, 0.f, 0.f, 0.f};

    const bf16* Ab = Cwp + ((size_t)((b * 128 + ctile * 8 + wid * 2) * 4)) * 512 + lane * 8;
    const bf16* Bb = Qbp + ((size_t)((b * 16 + qt * 4) * 4)) * 512 + lane * 8;
#pragma unroll
    for (int ks = 0; ks < 4; ++ks) {
        bf16x8 a0 = *(const bf16x8*)(Ab + (size_t)ks * 512);
        bf16x8 a1 = *(const bf16x8*)(Ab + (size_t)(4 + ks) * 512);
#pragma unroll
        for (int ct = 0; ct < 4; ++ct) {
            bf16x8 bb = *(const bf16x8*)(Bb + (size_t)(ct * 4 + ks) * 512);
            acc[0][ct] = MFMA16(a0, bb, acc[0][ct]);
            acc[1][ct] = MFMA16(a1, bb, acc[1][ct]);
        }
    }

    float biasv = bias[0];
    float sub0v[2][4], cmv[2][4];
#pragma unroll
    for (int rt = 0; rt < 2; ++rt)
#pragma unroll
        for (int j = 0; j < 4; ++j) {
            int idx = b * LC + rowbase + rt * 16 + lg * 4 + j;
            sub0v[rt][j] = sub0[idx];
            cmv[rt][j] = Cmask[idx];
        }

    float rsum[2][4] = {};
#pragma unroll
    for (int ct = 0; ct < 4; ++ct) {
        int q = q0 + ct * 16 + lr;
        float s1v = sub1[b * LQ + q] + biasv;
        float qm = Qmask[b * LQ + q];
        float colsum = 0.f;
#pragma unroll
        for (int rt = 0; rt < 2; ++rt)
#pragma unroll
            for (int j = 0; j < 4; ++j) {
                float S = acc[rt][ct][j] + sub0v[rt][j] + s1v;
                float Pv = __expf(S - 8.0f) * qm;
                rsum[rt][j] += Pv;
                colsum += Pv * cmv[rt][j];
                ldsP[wid * 32 + rt * 16 + lg * 4 + j][ct * 16 + lr] = (bf16)Pv;
            }
        colsum += __shfl_xor(colsum, 16);
        colsum += __shfl_xor(colsum, 32);
        if (lg == 0)
            Lpart[((size_t)(b * 64 + ctile * 4 + wid)) * LQ + q] = colsum;
    }
#pragma unroll
    for (int rt = 0; rt < 2; ++rt)
#pragma unroll
        for (int j = 0; j < 4; ++j) {
            float s = rsum[rt][j];
            s += __shfl_xor(s, 1);
            s += __shfl_xor(s, 2);
            s += __shfl_xor(s, 4);
            s += __shfl_xor(s, 8);
            if (lr == 0)
                Rpart[((size_t)(b * 4 + qt)) * LC + rowbase + rt * 16 + lg * 4 + j] = s;
        }
    __syncthreads();

    // Pp panels: 16 chunks (cb_l 0..7, ks_l 0..1), lane-linear
#pragma unroll
    for (int p = 0; p < 4; ++p) {
        int idx = p * 256 + t;
        int chunk = idx >> 6, w = idx & 63;
        int cb_l = chunk >> 1, ks_l = chunk & 1;
        int plr = w & 15, plg = w >> 4;
        bf16x8 v = *(bf16x8*)&ldsP[cb_l * 16 + plr][ks_l * 32 + plg * 8];
        size_t off = ((size_t)((b * 128 + ctile * 8 + cb_l) * 8 + qt * 2 + ks_l)) * 512 + w * 8;
        *(bf16x8*)(Pp + off) = v;
    }
}

// ---------------------------------------------------------------------------
// K3: 4-way K-split GEMM: MTp slice = sum over 512 c of (CbT*Cmask)[d][c]*P[c][q]
//   Cmask applied in-register to A-fragments (broadcast loads; exact 0/1).
//   B-operand via transpose-on-ds_write from Pp (plain loads -> L2/L3 hits).
// grid 1024 1D (XCD-swizzled); 16 K-steps; double-buffered.
// ---------------------------------------------------------------------------
__global__ __launch_bounds__(256) void k_m(const bf16* __restrict__ CbTp,
    const bf16* __restrict__ Pp, const float* __restrict__ Cmask,
    bf16* __restrict__ MTp)
{
    __shared__ bf16 stage[2][64 * 40];   // 2 x 5120 B
    int id = blockIdx.x;
    int xcd = id & 7, slot = id >> 3;            // same-b -> same XCD
    int b = xcd * 8 + (slot >> 4);
    int rem = slot & 15;
    int qt = rem & 3, ksl = rem >> 2;
    int t = threadIdx.x, wid = t >> 6, lane = t & 63;
    int lr = lane & 15, lg = lane >> 4;
    int dbase = wid * 32;

    f32x4 acc[2][4];
#pragma unroll
    for (int rt = 0; rt < 2; ++rt)
#pragma unroll
        for (int ct = 0; ct < 4; ++ct) acc[rt][ct] = (f32x4){0.f, 0.f, 0.f, 0.f};

    const bf16* Ab = CbTp + ((size_t)(b * 64 + ksl * 16) * 128 + dbase + lr) * 32 + lg * 8;
    const float* Mb = Cmask + b * LC + ksl * 512 + lg * 8;
    int cb_off = wid & 1, qh = wid >> 1;
    const bf16* Bsrc = Pp + ((size_t)((b * 128 + ksl * 32 + cb_off) * 8) + qt * 2 + qh) * 512
                       + lane * 8;
    int c_local = cb_off * 16 + lr;
    int qrow = qh * 32 + lg * 8;

    {
        bf16x8 g = *(const bf16x8*)Bsrc;
#pragma unroll
        for (int i = 0; i < 8; ++i) stage[0][(qrow + i) * 40 + c_local] = g[i];
    }
    __syncthreads();

    for (int ks = 0; ks < 16; ++ks) {
        int cur = ks & 1;
        bf16x8 g;
        if (ks < 15) g = *(const bf16x8*)(Bsrc + (size_t)(ks + 1) * 8192);
        bf16x8 a0 = *(const bf16x8*)(Ab + (size_t)ks * 4096);
        bf16x8 a1 = *(const bf16x8*)(Ab + (size_t)ks * 4096 + 512);
        // apply Cmask (0/1) to A-fragments: c = ksl*512 + ks*32 + lg*8 + i
        f32x4 m0 = *(const f32x4*)(Mb + ks * 32);
        f32x4 m1 = *(const f32x4*)(Mb + ks * 32 + 4);
        bf16x8 msk;
#pragma unroll
        for (int i = 0; i < 4; ++i) { msk[i] = (bf16)m0[i]; msk[4 + i] = (bf16)m1[i]; }
        a0 = a0 * msk;
        a1 = a1 * msk;
#pragma unroll
        for (int ct = 0; ct < 4; ++ct) {
            bf16x8 bb = *(bf16x8*)&stage[cur][(ct * 16 + lr) * 40 + lg * 8];
            acc[0][ct] = MFMA16(a0, bb, acc[0][ct]);
            acc[1][ct] = MFMA16(a1, bb, acc[1][ct]);
        }
        if (ks < 15) {
#pragma unroll
            for (int i = 0; i < 8; ++i) stage[cur ^ 1][(qrow + i) * 40 + c_local] = g[i];
        }
        __syncthreads();
    }

    size_t base = ((((size_t)ksl * B_ + b) * 4 + qt) * 4 + wid) * 2048;
#pragma unroll
    for (int rt = 0; rt < 2; ++rt)
#pragma unroll
        for (int ct = 0; ct < 4; ++ct)
#pragma unroll
            for (int j = 0; j < 4; ++j)
                MTp[base + (size_t)(rt * 16 + ct * 4 + j) * 64 + lane] = (bf16)acc[rt][ct][j];
}

// ---------------------------------------------------------------------------
// K4: reduce 4 K-slices + fold Linv -> MTpn (lane-linear chunks)
// grid (4, B), 256 thr
// ---------------------------------------------------------------------------
__global__ __launch_bounds__(256) void k_m2(const bf16* __restrict__ MTp,
    const float* __restrict__ Lpart, bf16* __restrict__ MTpn)
{
    __shared__ float ldsLinv[256];
    int b = blockIdx.y, ih = blockIdx.x;
    int t = threadIdx.x;
    {
        float s = 0.f;
#pragma unroll
        for (int sl = 0; sl < 64; ++sl) s += Lpart[((size_t)(b * 64 + sl)) * LQ + t];
        ldsLinv[t] = 1.0f / fmaxf(s, 1e-30f);
    }
    __syncthreads();
#pragma unroll
    for (int i = 0; i < 4; ++i) {
        int slot = (ih * 4 + i) * 256 + t;    // 0..4095
        int d = slot >> 5, qo = slot & 31;
        int q0 = qo * 8;
        int qt = q0 >> 6, ct = (q0 >> 4) & 3, lr0 = q0 & 15;
        int wid = d >> 5, rt = (d >> 4) & 1, lgd = (d >> 2) & 3, j = d & 3;
        size_t roff = ((size_t)(b * 4 + qt)) * 8192 + wid * 2048
                      + (rt * 16 + ct * 4 + j) * 64 + lgd * 16 + lr0;
        float a8[8] = {0.f, 0.f, 0.f, 0.f, 0.f, 0.f, 0.f, 0.f};
#pragma unroll
        for (int sl = 0; sl < 4; ++sl) {
            bf16x8 x = *(const bf16x8*)(MTp + (size_t)sl * B_ * 32768 + roff);
#pragma unroll
            for (int k = 0; k < 8; ++k) a8[k] += (float)x[k];
        }
        bf16x8 o;
#pragma unroll
        for (int k = 0; k < 8; ++k) o[k] = (bf16)(a8[k] * ldsLinv[q0 + k]);
        size_t woff = ((size_t)((b * 8 + (qo >> 2)) * 8 + (d >> 4))) * 512
                      + ((qo & 3) * 16 + (d & 15)) * 8;
        *(bf16x8*)(MTpn + woff) = o;
    }
}

// ---------------------------------------------------------------------------
// K5: A = Rinv*(P@Qb), Bt = Rinv*(P@M). C from CbTp (bf16), PREFETCHED before
//   the epilogue barrier. NT stores for out blocks 1-3; plain loads.
// grid 2048 1D (XCD-swizzled)
// ---------------------------------------------------------------------------
__global__ __launch_bounds__(256) void k_out(const bf16* __restrict__ Pp,
    const bf16* __restrict__ QbTp, const bf16* __restrict__ MTpn,
    const bf16* __restrict__ CbTp, const float* __restrict__ Rpart,
    float* __restrict__ out)
{
    __shared__ f32x4 smem4[2304];                       // 36864 B
    bf16* stage = (bf16*)smem4;                         // stage[2][8192] (32 KB)
    bf16 (*ldsA)[72] = (bf16(*)[72])smem4;              // epilogue-only (union)
    bf16 (*ldsB)[72] = (bf16(*)[72])((char*)smem4 + 18432);

    int id = blockIdx.x;
    int xcd = id & 7, slot = id >> 3;            // same-b -> same XCD
    int b = xcd * 8 + (slot >> 5);
    int ctile = slot & 31;
    int t = threadIdx.x, wid = t >> 6, lane = t & 63;
    int lr = lane & 15, lg = lane >> 4;
    int c0 = ctile * 64;

    const bf16* gsrc = (wid < 2 ? QbTp : MTpn) + (size_t)b * 32768
                       + (size_t)(wid & 1) * 2048 + lane * 8;
    int ldst = wid * 2048 + lane * 8;

    f32x4 rs = (f32x4){0.f, 0.f, 0.f, 0.f};
#pragma unroll
    for (int s = 0; s < 4; ++s)
        rs += *(const f32x4*)(Rpart + ((size_t)(b * 4 + s)) * LC + c0 + wid * 16 + lg * 4);
    f32x4 rv;
#pragma unroll
    for (int j = 0; j < 4; ++j) rv[j] = 1.0f / fmaxf(rs[j], 1e-30f);

    f32x4 accA[8], accB[8];
#pragma unroll
    for (int dt = 0; dt < 8; ++dt) {
        accA[dt] = (f32x4){0.f, 0.f, 0.f, 0.f};
        accB[dt] = (f32x4){0.f, 0.f, 0.f, 0.f};
    }
    const bf16* Ab = Pp + ((size_t)((b * 128 + ctile * 4 + wid) * 8)) * 512 + lane * 8;

    {
        bf16x8 g0 = *(const bf16x8*)(gsrc);
        bf16x8 g1 = *(const bf16x8*)(gsrc + 512);
        bf16x8 g2 = *(const bf16x8*)(gsrc + 1024);
        bf16x8 g3 = *(const bf16x8*)(gsrc + 1536);
        *(bf16x8*)&stage[ldst]        = g0;
        *(bf16x8*)&stage[ldst + 512]  = g1;
        *(bf16x8*)&stage[ldst + 1024] = g2;
        *(bf16x8*)&stage[ldst + 1536] = g3;
    }
    __syncthreads();

    for (int ks = 0; ks < 8; ++ks) {
        int cur = (ks & 1) * 8192;
        bf16x8 g0, g1, g2, g3;
        if (ks < 7) {
            const bf16* gs = gsrc + (size_t)(ks + 1) * 4096;
            g0 = *(const bf16x8*)(gs);
            g1 = *(const bf16x8*)(gs + 512);
            g2 = *(const bf16x8*)(gs + 1024);
            g3 = *(const bf16x8*)(gs + 1536);
        }
        bf16x8 a = *(const bf16x8*)(Ab + (size_t)ks * 512);
        int foff = cur + lane * 8;
#pragma unroll
        for (int dt = 0; dt < 8; ++dt) {
            bf16x8 bq = *(bf16x8*)&stage[foff + dt * 512];
            bf16x8 bm = *(bf16x8*)&stage[foff + 4096 + dt * 512];
            accA[dt] = MFMA16(a, bq, accA[dt]);
            accB[dt] = MFMA16(a, bm, accB[dt]);
        }
        if (ks < 7) {
            int nb = cur ^ 8192;
            *(bf16x8*)&stage[nb + ldst]        = g0;
            *(bf16x8*)&stage[nb + ldst + 512]  = g1;
            *(bf16x8*)&stage[nb + ldst + 1024] = g2;
            *(bf16x8*)&stage[nb + ldst + 1536] = g3;
        }
        __syncthreads();
    }

    // prefetch epilogue C^T (independent of LDS; overlaps transpose phase)
    int fsub = t >> 4;
    int cq = (t & 15) * 4;
    int cglob = c0 + cq;
    int cb32g = cglob >> 5, cig = cglob & 31;
    bf16x4 cpre[8];
#pragma unroll
    for (int pass = 0; pass < 8; ++pass) {
        int d = pass * 16 + fsub;
        cpre[pass] = *(const bf16x4*)(CbTp + ((size_t)(b * 64 + cb32g) * 128 + d) * 32 + cig);
    }

#pragma unroll
    for (int dt = 0; dt < 8; ++dt) {
        f32x4 a4 = accA[dt] * rv;
        f32x4 b4 = accB[dt] * rv;
        bf16x4 pa = { (bf16)a4[0], (bf16)a4[1], (bf16)a4[2], (bf16)a4[3] };
        bf16x4 pb = { (bf16)b4[0], (bf16)b4[1], (bf16)b4[2], (bf16)b4[3] };
        *(bf16x4*)&ldsA[dt * 16 + lr][wid * 16 + lg * 4] = pa;
        *(bf16x4*)&ldsB[dt * 16 + lr][wid * 16 + lg * 4] = pb;
    }
    __syncthreads();

    float* obase = out + ((size_t)b * 512) * LC;
#pragma unroll
    for (int pass = 0; pass < 8; ++pass) {
        int d = pass * 16 + fsub;
        bf16x4 av = *(bf16x4*)&ldsA[d][cq];
        bf16x4 bv = *(bf16x4*)&ldsB[d][cq];
        bf16x4 cb4 = cpre[pass];
        f32x4 c4 = {(float)cb4[0], (float)cb4[1], (float)cb4[2], (float)cb4[3]};
        f32x4 a4 = {(float)av[0], (float)av[1], (float)av[2], (float)av[3]};
        f32x4 b4 = {(float)bv[0], (float)bv[1], (float)bv[2], (float)bv[3]};
        __builtin_nontemporal_store(a4, (f32x4*)(obase + (size_t)(128 + d) * LC + c0 + cq));
        __builtin_nontemporal_store(c4 * a4, (f32x4*)(obase + (size_t)(256 + d) * LC + c0 + cq));
        __builtin_nontemporal_store(c4 * b4, (f32x4*)(obase + (size_t)(384 + d) * LC + c0 + cq));
    }
}

// ---------------------------------------------------------------------------
extern "C" void kernel_launch(void* const* d_in, const int* in_sizes, int n_in,
                              void* d_out, int out_size, void* d_ws, size_t ws_size,
                              hipStream_t stream)
{
    const float* C     = (const float*)d_in[0];
    const float* Q     = (const float*)d_in[1];
    const float* Cmask = (const float*)d_in[2];
    const float* Qmask = (const float*)d_in[3];
    const float* w4C   = (const float*)d_in[4];
    const float* w4Q   = (const float*)d_in[5];
    const float* w4mlu = (const float*)d_in[6];
    const float* bias  = (const float*)d_in[7];
    float* out = (float*)d_out;

    char* ws = (char*)d_ws;
    size_t off = 0;
    auto alloc = [&](size_t bytes) -> char* {
        char* p = ws + off;
        off += (bytes + 255) & ~(size_t)255;
        return p;
    };
    bf16* Cwp   = (bf16*)alloc((size_t)B_ * LC * DD * 2);
    bf16* CbTp  = (bf16*)alloc((size_t)B_ * LC * DD * 2);
    bf16* Qbp   = (bf16*)alloc((size_t)B_ * LQ * DD * 2);
    bf16* QbTp  = (bf16*)alloc((size_t)B_ * LQ * DD * 2);
    bf16* Pp    = (bf16*)alloc((size_t)B_ * LC * LQ * 2);
    bf16* MTp   = (bf16*)alloc((size_t)4 * B_ * DD * LQ * 2);
    bf16* MTpn  = (bf16*)alloc((size_t)B_ * DD * LQ * 2);
    float* sub0 = (float*)alloc((size_t)B_ * LC * 4);
    float* sub1 = (float*)alloc((size_t)B_ * LQ * 4);
    float* Rpart = (float*)alloc((size_t)B_ * 4 * LC * 4);
    float* Lpart = (float*)alloc((size_t)B_ * 64 * LQ * 4);
    (void)ws_size; (void)in_sizes; (void)n_in; (void)out_size;

    hipLaunchKernelGGL(k_prep, dim3(2304), dim3(256), 0, stream,
                       C, Q, w4C, w4Q, w4mlu, Cwp, CbTp, Qbp, QbTp, sub0, sub1, out);
    hipLaunchKernelGGL(k_s, dim3(4096), dim3(256), 0, stream,
                       Cwp, Qbp, sub0, sub1, Qmask, Cmask, bias, Pp, Rpart, Lpart);
    hipLaunchKernelGGL(k_m, dim3(1024), dim3(256), 0, stream, CbTp, Pp, Cmask, MTp);
    hipLaunchKernelGGL(k_m2, dim3(4, B_), dim3(256), 0, stream, MTp, Lpart, MTpn);
    hipLaunchKernelGGL(k_out, dim3(2048), dim3(256), 0, stream,
                       Pp, QbTp, MTpn, CbTp, Rpart, out);
}

// Round 16
// 150.228 us; speedup vs baseline: 1.4656x; 1.0402x over previous
//
#include <hip/hip_runtime.h>

#define B_ 64
#define LC 2048
#define LQ 256
#define DD 128

typedef __bf16 bf16;
typedef __bf16 bf16x8 __attribute__((ext_vector_type(8)));
typedef __bf16 bf16x4 __attribute__((ext_vector_type(4)));
typedef float f32x4 __attribute__((ext_vector_type(4)));

#define MFMA16(a, b, c) __builtin_amdgcn_mfma_f32_16x16x32_bf16((a), (b), (c), 0, 0, 0)

// Panel layouts (bf16, chunk = 512 elems = 1KB), within-chunk LANE-LINEAR.
//  Cwp   [b][cb][ks 4][512]   Qbp [b][qb][ks 4][512]   QbTp [b][ks][dt 8][512]
//  CbTp  [b][cb32][d 128][32]  (UNmasked; Cmask in-register in k_sm M-GEMM)
//  Pp    [b][cb][ks 8][512]    MTpn [b][ks 8][dt 8][512] (Linv folded)
// k_sm fuses k_s + k_m: block = (qt 64q, ksl 512c); 4 subtiles of 128c;
// P kept in LDS (ldsP for Pp pack, ldsPT [q][c] for M-GEMM); M accumulated
// in registers across subtiles -> Pp never re-read from HBM by the M path.
// XCD swizzle everywhere: same-b blocks co-located. NT stores on out only.

// ---------------------------------------------------------------------------
// K1 (merged preps): blocks 0..2047 = C path; 2048..2303 = Q path.
// ---------------------------------------------------------------------------
__global__ __launch_bounds__(256) void k_prep(const float* __restrict__ C,
    const float* __restrict__ Q, const float* __restrict__ w4C,
    const float* __restrict__ w4Q, const float* __restrict__ w4mlu,
    bf16* __restrict__ Cwp, bf16* __restrict__ CbTp,
    bf16* __restrict__ Qbp, bf16* __restrict__ QbTp,
    float* __restrict__ sub0, float* __restrict__ sub1, float* __restrict__ out)
{
    __shared__ float lds[64][DD + 4];
    int t = threadIdx.x;
    if (blockIdx.x < 2048) {
        int b = blockIdx.x >> 5, ct = blockIdx.x & 31;
        int c0 = ct * 64;
        int r = t >> 2, cb = (t & 3) * 32;
        size_t rowoff = ((size_t)(b * LC + c0 + r)) * DD + cb;
        const float4* src = (const float4*)(C + rowoff);
        float s0 = 0.f;
#pragma unroll
        for (int i = 0; i < 8; ++i) {
            float4 v = src[i];
            int d = cb + i * 4;
            lds[r][d] = v.x; lds[r][d + 1] = v.y; lds[r][d + 2] = v.z; lds[r][d + 3] = v.w;
            s0 += v.x * w4C[d] + v.y * w4C[d + 1] + v.z * w4C[d + 2] + v.w * w4C[d + 3];
        }
        s0 += __shfl_xor(s0, 1);
        s0 += __shfl_xor(s0, 2);
        if ((t & 3) == 0) sub0[b * LC + c0 + r] = s0;
        __syncthreads();

#pragma unroll
        for (int p = 0; p < 4; ++p) {
            int idx = p * 256 + t;
            int chunk = idx >> 6, w = idx & 63;
            int cb_l = chunk >> 2, ks = chunk & 3;
            int lr = w & 15, lg = w >> 4;
            int c_l = cb_l * 16 + lr, d0 = ks * 32 + lg * 8;
            bf16x8 v;
#pragma unroll
            for (int j = 0; j < 8; ++j) v[j] = (bf16)(lds[c_l][d0 + j] * w4mlu[d0 + j]);
            size_t off = ((size_t)((b * 128 + ct * 4 + cb_l) * 4 + ks)) * 512 + w * 8;
            *(bf16x8*)(Cwp + off) = v;
        }
        // CbTp panels (UNmasked)
#pragma unroll
        for (int p = 0; p < 4; ++p) {
            int idx = p * 256 + t;
            int cb32 = idx >> 9, rem = idx & 511;
            int d = rem >> 2, lg = rem & 3;
            int cl0 = cb32 * 32 + lg * 8;
            bf16x8 v;
#pragma unroll
            for (int j = 0; j < 8; ++j) v[j] = (bf16)lds[cl0 + j][d];
            size_t off = ((size_t)((b * 64 + ct * 2 + cb32) * 128 + d)) * 32 + lg * 8;
            *(bf16x8*)(CbTp + off) = v;
        }
        // out block 0: exact fp32 C^T, NT stores (never re-read)
#pragma unroll
        for (int p = 0; p < 8; ++p) {
            int d = p * 16 + (t >> 4);
            int cl = (t & 15) * 4;
            f32x4 v = {lds[cl][d], lds[cl + 1][d], lds[cl + 2][d], lds[cl + 3][d]};
            __builtin_nontemporal_store(v,
                (f32x4*)(out + ((size_t)(b * 512 + d)) * LC + c0 + cl));
        }
    } else {
        int idx0 = blockIdx.x - 2048;
        int b = idx0 >> 2, qt = idx0 & 3;
        int q0 = qt * 64;
        bf16* ldsb = (bf16*)lds;   // reuse as bf16 [64][132]
        int r = t >> 2, cb = (t & 3) * 32;
        size_t rowoff = ((size_t)(b * LQ + q0 + r)) * DD + cb;
        const float4* src = (const float4*)(Q + rowoff);
        float s1 = 0.f;
#pragma unroll
        for (int i = 0; i < 8; ++i) {
            float4 v = src[i];
            int d = cb + i * 4;
            ldsb[r * 132 + d] = (bf16)v.x; ldsb[r * 132 + d + 1] = (bf16)v.y;
            ldsb[r * 132 + d + 2] = (bf16)v.z; ldsb[r * 132 + d + 3] = (bf16)v.w;
            s1 += v.x * w4Q[d] + v.y * w4Q[d + 1] + v.z * w4Q[d + 2] + v.w * w4Q[d + 3];
        }
        s1 += __shfl_xor(s1, 1);
        s1 += __shfl_xor(s1, 2);
        if ((t & 3) == 0) sub1[b * LQ + q0 + r] = s1;
        __syncthreads();

#pragma unroll
        for (int p = 0; p < 4; ++p) {
            int idx = p * 256 + t;
            int chunk = idx >> 6, w = idx & 63;
            int qb_l = chunk >> 2, ks = chunk & 3;
            int lr = w & 15, lg = w >> 4;
            bf16x8 v = *(bf16x8*)&ldsb[(qb_l * 16 + lr) * 132 + ks * 32 + lg * 8];
            size_t off = ((size_t)((b * 16 + qt * 4 + qb_l) * 4 + ks)) * 512 + w * 8;
            *(bf16x8*)(Qbp + off) = v;
        }
#pragma unroll
        for (int p = 0; p < 4; ++p) {
            int idx = p * 256 + t;
            int chunk = idx >> 6, w = idx & 63;
            int ks_l = chunk >> 3, dt = chunk & 7;
            int lr = w & 15, lg = w >> 4;
            int d = dt * 16 + lr, ql = ks_l * 32 + lg * 8;
            bf16x8 v;
#pragma unroll
            for (int j = 0; j < 8; ++j) v[j] = ldsb[(ql + j) * 132 + d];
            size_t off = ((size_t)((b * 8 + qt * 2 + ks_l) * 8 + dt)) * 512 + w * 8;
            *(bf16x8*)(QbTp + off) = v;
        }
    }
}

// ---------------------------------------------------------------------------
// K2 (fused k_s + k_m): block = (qt: 64 q, ksl: 512 c), 4 subtiles of 128 c.
//   Per subtile: S = Cw@Qb^T + subs + bias; P = Qm*exp(S-8); pack ldsP
//   ([c][q], for Pp store) and ldsPT ([q][c], M-GEMM operand); accumulate
//   accM += (CbT*Cmask)[d][c] @ P^T[c][q] from LDS. Finale: MTp slice store.
// grid 1024 1D (XCD-swizzled, same-b co-located); 4 waves; LDS 38.4 KB.
// ---------------------------------------------------------------------------
__global__ __launch_bounds__(256) void k_sm(const bf16* __restrict__ Cwp,
    const bf16* __restrict__ Qbp, const bf16* __restrict__ CbTp,
    const float* __restrict__ sub0, const float* __restrict__ sub1,
    const float* __restrict__ Qmask, const float* __restrict__ Cmask,
    const float* __restrict__ bias,
    bf16* __restrict__ Pp, float* __restrict__ Rpart, float* __restrict__ Lpart,
    bf16* __restrict__ MTp)
{
    __shared__ bf16 ldsP[128][82];    // [c_local][q_local]
    __shared__ bf16 ldsPT[64][136];   // [q_local][c_local]
    int id = blockIdx.x;
    int xcd = id & 7, slot = id >> 3;            // same-b -> same XCD
    int b = xcd * 8 + (slot >> 4);
    int rem = slot & 15;
    int qt = rem & 3, ksl = rem >> 2;
    int q0 = qt * 64;
    int t = threadIdx.x, wid = t >> 6, lane = t & 63;
    int lr = lane & 15, lg = lane >> 4;
    int dbase = wid * 32;

    float biasv = bias[0];
    float s1v[4], qmv[4];
#pragma unroll
    for (int ct = 0; ct < 4; ++ct) {
        int q = q0 + ct * 16 + lr;
        s1v[ct] = sub1[b * LQ + q] + biasv;
        qmv[ct] = Qmask[b * LQ + q];
    }

    f32x4 accM[2][4];
#pragma unroll
    for (int rt = 0; rt < 2; ++rt)
#pragma unroll
        for (int ct = 0; ct < 4; ++ct) accM[rt][ct] = (f32x4){0.f, 0.f, 0.f, 0.f};

    const bf16* Am_base = CbTp + ((size_t)(b * 64 + ksl * 16) * 128 + dbase + lr) * 32 + lg * 8;
    const float* Mb = Cmask + b * LC + ksl * 512 + lg * 8;
    const bf16* Bb = Qbp + ((size_t)((b * 16 + qt * 4) * 4)) * 512 + lane * 8;

    for (int st = 0; st < 4; ++st) {
        int ctile = ksl * 4 + st;
        int rowbase = ctile * 128 + wid * 32;

        // ---- S GEMM (128c x 64q) ----
        f32x4 acc[2][4];
#pragma unroll
        for (int rt = 0; rt < 2; ++rt)
#pragma unroll
            for (int ct = 0; ct < 4; ++ct) acc[rt][ct] = (f32x4){0.f, 0.f, 0.f, 0.f};
        const bf16* Ab = Cwp + ((size_t)((b * 128 + ctile * 8 + wid * 2) * 4)) * 512 + lane * 8;
#pragma unroll
        for (int ks = 0; ks < 4; ++ks) {
            bf16x8 a0 = *(const bf16x8*)(Ab + (size_t)ks * 512);
            bf16x8 a1 = *(const bf16x8*)(Ab + (size_t)(4 + ks) * 512);
#pragma unroll
            for (int ct = 0; ct < 4; ++ct) {
                bf16x8 bb = *(const bf16x8*)(Bb + (size_t)(ct * 4 + ks) * 512);
                acc[0][ct] = MFMA16(a0, bb, acc[0][ct]);
                acc[1][ct] = MFMA16(a1, bb, acc[1][ct]);
            }
        }

        float sub0v[2][4], cmv[2][4];
#pragma unroll
        for (int rt = 0; rt < 2; ++rt)
#pragma unroll
            for (int j = 0; j < 4; ++j) {
                int idx = b * LC + rowbase + rt * 16 + lg * 4 + j;
                sub0v[rt][j] = sub0[idx];
                cmv[rt][j] = Cmask[idx];
            }

        // wait for previous subtile's LDS consumers
        __syncthreads();

        float rsum[2][4] = {};
#pragma unroll
        for (int ct = 0; ct < 4; ++ct) {
            float colsum = 0.f;
#pragma unroll
            for (int rt = 0; rt < 2; ++rt) {
                bf16x4 ptv;
#pragma unroll
                for (int j = 0; j < 4; ++j) {
                    float S = acc[rt][ct][j] + sub0v[rt][j] + s1v[ct];
                    float Pv = __expf(S - 8.0f) * qmv[ct];
                    rsum[rt][j] += Pv;
                    colsum += Pv * cmv[rt][j];
                    bf16 pb = (bf16)Pv;
                    ldsP[wid * 32 + rt * 16 + lg * 4 + j][ct * 16 + lr] = pb;
                    ptv[j] = pb;
                }
                *(bf16x4*)&ldsPT[ct * 16 + lr][wid * 32 + rt * 16 + lg * 4] = ptv;
            }
            colsum += __shfl_xor(colsum, 16);
            colsum += __shfl_xor(colsum, 32);
            if (lg == 0)
                Lpart[((size_t)(b * 64 + ctile * 4 + wid)) * LQ + q0 + ct * 16 + lr] = colsum;
        }
#pragma unroll
        for (int rt = 0; rt < 2; ++rt)
#pragma unroll
            for (int j = 0; j < 4; ++j) {
                float s = rsum[rt][j];
                s += __shfl_xor(s, 1);
                s += __shfl_xor(s, 2);
                s += __shfl_xor(s, 4);
                s += __shfl_xor(s, 8);
                if (lr == 0)
                    Rpart[((size_t)(b * 4 + qt)) * LC + rowbase + rt * 16 + lg * 4 + j] = s;
            }
        __syncthreads();

        // ---- Pp panel store (16 chunks: cb_l 0..7, ks_l 0..1) ----
#pragma unroll
        for (int p = 0; p < 4; ++p) {
            int idx = p * 256 + t;
            int chunk = idx >> 6, w = idx & 63;
            int cb_l = chunk >> 1, ks_l = chunk & 1;
            int plr = w & 15, plg = w >> 4;
            bf16x8 v = *(bf16x8*)&ldsP[cb_l * 16 + plr][ks_l * 32 + plg * 8];
            size_t off = ((size_t)((b * 128 + ctile * 8 + cb_l) * 8 + qt * 2 + ks_l)) * 512 + w * 8;
            *(bf16x8*)(Pp + off) = v;
        }

        // ---- M GEMM accumulate from ldsPT: K = this subtile's 128 c ----
#pragma unroll
        for (int kf = 0; kf < 4; ++kf) {
            int ks = st * 4 + kf;
            bf16x8 a0 = *(const bf16x8*)(Am_base + (size_t)ks * 4096);
            bf16x8 a1 = *(const bf16x8*)(Am_base + (size_t)ks * 4096 + 512);
            f32x4 m0 = *(const f32x4*)(Mb + ks * 32);
            f32x4 m1 = *(const f32x4*)(Mb + ks * 32 + 4);
            bf16x8 msk;
#pragma unroll
            for (int i = 0; i < 4; ++i) { msk[i] = (bf16)m0[i]; msk[4 + i] = (bf16)m1[i]; }
            a0 = a0 * msk;
            a1 = a1 * msk;
#pragma unroll
            for (int ct = 0; ct < 4; ++ct) {
                bf16x8 bb = *(bf16x8*)&ldsPT[ct * 16 + lr][kf * 32 + lg * 8];
                accM[0][ct] = MFMA16(a0, bb, accM[0][ct]);
                accM[1][ct] = MFMA16(a1, bb, accM[1][ct]);
            }
        }
    }

    // ---- MTp slice store (native flat layout, same as old k_m) ----
    size_t base = ((((size_t)ksl * B_ + b) * 4 + qt) * 4 + wid) * 2048;
#pragma unroll
    for (int rt = 0; rt < 2; ++rt)
#pragma unroll
        for (int ct = 0; ct < 4; ++ct)
#pragma unroll
            for (int j = 0; j < 4; ++j)
                MTp[base + (size_t)(rt * 16 + ct * 4 + j) * 64 + lane] = (bf16)accM[rt][ct][j];
}

// ---------------------------------------------------------------------------
// K3: reduce 4 K-slices + fold Linv -> MTpn (lane-linear chunks)
// grid (4, B), 256 thr
// ---------------------------------------------------------------------------
__global__ __launch_bounds__(256) void k_m2(const bf16* __restrict__ MTp,
    const float* __restrict__ Lpart, bf16* __restrict__ MTpn)
{
    __shared__ float ldsLinv[256];
    int b = blockIdx.y, ih = blockIdx.x;
    int t = threadIdx.x;
    {
        float s = 0.f;
#pragma unroll
        for (int sl = 0; sl < 64; ++sl) s += Lpart[((size_t)(b * 64 + sl)) * LQ + t];
        ldsLinv[t] = 1.0f / fmaxf(s, 1e-30f);
    }
    __syncthreads();
#pragma unroll
    for (int i = 0; i < 4; ++i) {
        int slot = (ih * 4 + i) * 256 + t;    // 0..4095
        int d = slot >> 5, qo = slot & 31;
        int q0 = qo * 8;
        int qt = q0 >> 6, ct = (q0 >> 4) & 3, lr0 = q0 & 15;
        int wid = d >> 5, rt = (d >> 4) & 1, lgd = (d >> 2) & 3, j = d & 3;
        size_t roff = ((size_t)(b * 4 + qt)) * 8192 + wid * 2048
                      + (rt * 16 + ct * 4 + j) * 64 + lgd * 16 + lr0;
        float a8[8] = {0.f, 0.f, 0.f, 0.f, 0.f, 0.f, 0.f, 0.f};
#pragma unroll
        for (int sl = 0; sl < 4; ++sl) {
            bf16x8 x = *(const bf16x8*)(MTp + (size_t)sl * B_ * 32768 + roff);
#pragma unroll
            for (int k = 0; k < 8; ++k) a8[k] += (float)x[k];
        }
        bf16x8 o;
#pragma unroll
        for (int k = 0; k < 8; ++k) o[k] = (bf16)(a8[k] * ldsLinv[q0 + k]);
        size_t woff = ((size_t)((b * 8 + (qo >> 2)) * 8 + (d >> 4))) * 512
                      + ((qo & 3) * 16 + (d & 15)) * 8;
        *(bf16x8*)(MTpn + woff) = o;
    }
}

// ---------------------------------------------------------------------------
// K4: A = Rinv*(P@Qb), Bt = Rinv*(P@M). C from CbTp (bf16), prefetched.
//   NT stores for out blocks 1-3; plain loads. grid 2048 1D (XCD-swizzled)
// ---------------------------------------------------------------------------
__global__ __launch_bounds__(256) void k_out(const bf16* __restrict__ Pp,
    const bf16* __restrict__ QbTp, const bf16* __restrict__ MTpn,
    const bf16* __restrict__ CbTp, const float* __restrict__ Rpart,
    float* __restrict__ out)
{
    __shared__ f32x4 smem4[2304];                       // 36864 B
    bf16* stage = (bf16*)smem4;                         // stage[2][8192] (32 KB)
    bf16 (*ldsA)[72] = (bf16(*)[72])smem4;              // epilogue-only (union)
    bf16 (*ldsB)[72] = (bf16(*)[72])((char*)smem4 + 18432);

    int id = blockIdx.x;
    int xcd = id & 7, slot = id >> 3;            // same-b -> same XCD
    int b = xcd * 8 + (slot >> 5);
    int ctile = slot & 31;
    int t = threadIdx.x, wid = t >> 6, lane = t & 63;
    int lr = lane & 15, lg = lane >> 4;
    int c0 = ctile * 64;

    const bf16* gsrc = (wid < 2 ? QbTp : MTpn) + (size_t)b * 32768
                       + (size_t)(wid & 1) * 2048 + lane * 8;
    int ldst = wid * 2048 + lane * 8;

    f32x4 rs = (f32x4){0.f, 0.f, 0.f, 0.f};
#pragma unroll
    for (int s = 0; s < 4; ++s)
        rs += *(const f32x4*)(Rpart + ((size_t)(b * 4 + s)) * LC + c0 + wid * 16 + lg * 4);
    f32x4 rv;
#pragma unroll
    for (int j = 0; j < 4; ++j) rv[j] = 1.0f / fmaxf(rs[j], 1e-30f);

    f32x4 accA[8], accB[8];
#pragma unroll
    for (int dt = 0; dt < 8; ++dt) {
        accA[dt] = (f32x4){0.f, 0.f, 0.f, 0.f};
        accB[dt] = (f32x4){0.f, 0.f, 0.f, 0.f};
    }
    const bf16* Ab = Pp + ((size_t)((b * 128 + ctile * 4 + wid) * 8)) * 512 + lane * 8;

    {
        bf16x8 g0 = *(const bf16x8*)(gsrc);
        bf16x8 g1 = *(const bf16x8*)(gsrc + 512);
        bf16x8 g2 = *(const bf16x8*)(gsrc + 1024);
        bf16x8 g3 = *(const bf16x8*)(gsrc + 1536);
        *(bf16x8*)&stage[ldst]        = g0;
        *(bf16x8*)&stage[ldst + 512]  = g1;
        *(bf16x8*)&stage[ldst + 1024] = g2;
        *(bf16x8*)&stage[ldst + 1536] = g3;
    }
    __syncthreads();

    for (int ks = 0; ks < 8; ++ks) {
        int cur = (ks & 1) * 8192;
        bf16x8 g0, g1, g2, g3;
        if (ks < 7) {
            const bf16* gs = gsrc + (size_t)(ks + 1) * 4096;
            g0 = *(const bf16x8*)(gs);
            g1 = *(const bf16x8*)(gs + 512);
            g2 = *(const bf16x8*)(gs + 1024);
            g3 = *(const bf16x8*)(gs + 1536);
        }
        bf16x8 a = *(const bf16x8*)(Ab + (size_t)ks * 512);
        int foff = cur + lane * 8;
#pragma unroll
        for (int dt = 0; dt < 8; ++dt) {
            bf16x8 bq = *(bf16x8*)&stage[foff + dt * 512];
            bf16x8 bm = *(bf16x8*)&stage[foff + 4096 + dt * 512];
            accA[dt] = MFMA16(a, bq, accA[dt]);
            accB[dt] = MFMA16(a, bm, accB[dt]);
        }
        if (ks < 7) {
            int nb = cur ^ 8192;
            *(bf16x8*)&stage[nb + ldst]        = g0;
            *(bf16x8*)&stage[nb + ldst + 512]  = g1;
            *(bf16x8*)&stage[nb + ldst + 1024] = g2;
            *(bf16x8*)&stage[nb + ldst + 1536] = g3;
        }
        __syncthreads();
    }

    // prefetch epilogue C^T (independent of LDS; overlaps transpose phase)
    int fsub = t >> 4;
    int cq = (t & 15) * 4;
    int cglob = c0 + cq;
    int cb32g = cglob >> 5, cig = cglob & 31;
    bf16x4 cpre[8];
#pragma unroll
    for (int pass = 0; pass < 8; ++pass) {
        int d = pass * 16 + fsub;
        cpre[pass] = *(const bf16x4*)(CbTp + ((size_t)(b * 64 + cb32g) * 128 + d) * 32 + cig);
    }

#pragma unroll
    for (int dt = 0; dt < 8; ++dt) {
        f32x4 a4 = accA[dt] * rv;
        f32x4 b4 = accB[dt] * rv;
        bf16x4 pa = { (bf16)a4[0], (bf16)a4[1], (bf16)a4[2], (bf16)a4[3] };
        bf16x4 pb = { (bf16)b4[0], (bf16)b4[1], (bf16)b4[2], (bf16)b4[3] };
        *(bf16x4*)&ldsA[dt * 16 + lr][wid * 16 + lg * 4] = pa;
        *(bf16x4*)&ldsB[dt * 16 + lr][wid * 16 + lg * 4] = pb;
    }
    __syncthreads();

    float* obase = out + ((size_t)b * 512) * LC;
#pragma unroll
    for (int pass = 0; pass < 8; ++pass) {
        int d = pass * 16 + fsub;
        bf16x4 av = *(bf16x4*)&ldsA[d][cq];
        bf16x4 bv = *(bf16x4*)&ldsB[d][cq];
        bf16x4 cb4 = cpre[pass];
        f32x4 c4 = {(float)cb4[0], (float)cb4[1], (float)cb4[2], (float)cb4[3]};
        f32x4 a4 = {(float)av[0], (float)av[1], (float)av[2], (float)av[3]};
        f32x4 b4 = {(float)bv[0], (float)bv[1], (float)bv[2], (float)bv[3]};
        __builtin_nontemporal_store(a4, (f32x4*)(obase + (size_t)(128 + d) * LC + c0 + cq));
        __builtin_nontemporal_store(c4 * a4, (f32x4*)(obase + (size_t)(256 + d) * LC + c0 + cq));
        __builtin_nontemporal_store(c4 * b4, (f32x4*)(obase + (size_t)(384 + d) * LC + c0 + cq));
    }
}

// ---------------------------------------------------------------------------
extern "C" void kernel_launch(void* const* d_in, const int* in_sizes, int n_in,
                              void* d_out, int out_size, void* d_ws, size_t ws_size,
                              hipStream_t stream)
{
    const float* C     = (const float*)d_in[0];
    const float* Q     = (const float*)d_in[1];
    const float* Cmask = (const float*)d_in[2];
    const float* Qmask = (const float*)d_in[3];
    const float* w4C   = (const float*)d_in[4];
    const float* w4Q   = (const float*)d_in[5];
    const float* w4mlu = (const float*)d_in[6];
    const float* bias  = (const float*)d_in[7];
    float* out = (float*)d_out;

    char* ws = (char*)d_ws;
    size_t off = 0;
    auto alloc = [&](size_t bytes) -> char* {
        char* p = ws + off;
        off += (bytes + 255) & ~(size_t)255;
        return p;
    };
    bf16* Cwp   = (bf16*)alloc((size_t)B_ * LC * DD * 2);
    bf16* CbTp  = (bf16*)alloc((size_t)B_ * LC * DD * 2);
    bf16* Qbp   = (bf16*)alloc((size_t)B_ * LQ * DD * 2);
    bf16* QbTp  = (bf16*)alloc((size_t)B_ * LQ * DD * 2);
    bf16* Pp    = (bf16*)alloc((size_t)B_ * LC * LQ * 2);
    bf16* MTp   = (bf16*)alloc((size_t)4 * B_ * DD * LQ * 2);
    bf16* MTpn  = (bf16*)alloc((size_t)B_ * DD * LQ * 2);
    float* sub0 = (float*)alloc((size_t)B_ * LC * 4);
    float* sub1 = (float*)alloc((size_t)B_ * LQ * 4);
    float* Rpart = (float*)alloc((size_t)B_ * 4 * LC * 4);
    float* Lpart = (float*)alloc((size_t)B_ * 64 * LQ * 4);
    (void)ws_size; (void)in_sizes; (void)n_in; (void)out_size;

    hipLaunchKernelGGL(k_prep, dim3(2304), dim3(256), 0, stream,
                       C, Q, w4C, w4Q, w4mlu, Cwp, CbTp, Qbp, QbTp, sub0, sub1, out);
    hipLaunchKernelGGL(k_sm, dim3(1024), dim3(256), 0, stream,
                       Cwp, Qbp, CbTp, sub0, sub1, Qmask, Cmask, bias,
                       Pp, Rpart, Lpart, MTp);
    hipLaunchKernelGGL(k_m2, dim3(4, B_), dim3(256), 0, stream, MTp, Lpart, MTpn);
    hipLaunchKernelGGL(k_out, dim3(2048), dim3(256), 0, stream,
                       Pp, QbTp, MTpn, CbTp, Rpart, out);
}

// Round 17
// 150.004 us; speedup vs baseline: 1.4678x; 1.0015x over previous
//
#include <hip/hip_runtime.h>

#define B_ 64
#define LC 2048
#define LQ 256
#define DD 128

typedef __bf16 bf16;
typedef __bf16 bf16x8 __attribute__((ext_vector_type(8)));
typedef __bf16 bf16x4 __attribute__((ext_vector_type(4)));
typedef float f32x4 __attribute__((ext_vector_type(4)));

#define MFMA16(a, b, c) __builtin_amdgcn_mfma_f32_16x16x32_bf16((a), (b), (c), 0, 0, 0)

// Panel layouts (bf16, chunk = 512 elems = 1KB), within-chunk LANE-LINEAR.
//  Cwp   [b][cb][ks 4][512]   Qbp [b][qb][ks 4][512]   QbTp [b][ks][dt 8][512]
//  CbTp  [b][cb32][d 128][32]  (UNmasked; Cmask in-register in k_sm M-GEMM)
//  Pp    [b][cb][ks 8][512]    MTpn [b][ks 8][dt 8][512] (Linv folded)
// k_sm fuses k_s + k_m. XCD swizzle on ALL consumer kernels (k_sm, k_m2,
// k_out): xcd = id&7, b = xcd*8+...; every producer->consumer stream is
// same-XCD L2-local. NT stores on out only.

// ---------------------------------------------------------------------------
// K1 (merged preps): blocks 0..2047 = C path; 2048..2303 = Q path.
// ---------------------------------------------------------------------------
__global__ __launch_bounds__(256) void k_prep(const float* __restrict__ C,
    const float* __restrict__ Q, const float* __restrict__ w4C,
    const float* __restrict__ w4Q, const float* __restrict__ w4mlu,
    bf16* __restrict__ Cwp, bf16* __restrict__ CbTp,
    bf16* __restrict__ Qbp, bf16* __restrict__ QbTp,
    float* __restrict__ sub0, float* __restrict__ sub1, float* __restrict__ out)
{
    __shared__ float lds[64][DD + 4];
    int t = threadIdx.x;
    if (blockIdx.x < 2048) {
        int b = blockIdx.x >> 5, ct = blockIdx.x & 31;
        int c0 = ct * 64;
        int r = t >> 2, cb = (t & 3) * 32;
        size_t rowoff = ((size_t)(b * LC + c0 + r)) * DD + cb;
        const float4* src = (const float4*)(C + rowoff);
        float s0 = 0.f;
#pragma unroll
        for (int i = 0; i < 8; ++i) {
            float4 v = src[i];
            int d = cb + i * 4;
            lds[r][d] = v.x; lds[r][d + 1] = v.y; lds[r][d + 2] = v.z; lds[r][d + 3] = v.w;
            s0 += v.x * w4C[d] + v.y * w4C[d + 1] + v.z * w4C[d + 2] + v.w * w4C[d + 3];
        }
        s0 += __shfl_xor(s0, 1);
        s0 += __shfl_xor(s0, 2);
        if ((t & 3) == 0) sub0[b * LC + c0 + r] = s0;
        __syncthreads();

#pragma unroll
        for (int p = 0; p < 4; ++p) {
            int idx = p * 256 + t;
            int chunk = idx >> 6, w = idx & 63;
            int cb_l = chunk >> 2, ks = chunk & 3;
            int lr = w & 15, lg = w >> 4;
            int c_l = cb_l * 16 + lr, d0 = ks * 32 + lg * 8;
            bf16x8 v;
#pragma unroll
            for (int j = 0; j < 8; ++j) v[j] = (bf16)(lds[c_l][d0 + j] * w4mlu[d0 + j]);
            size_t off = ((size_t)((b * 128 + ct * 4 + cb_l) * 4 + ks)) * 512 + w * 8;
            *(bf16x8*)(Cwp + off) = v;
        }
        // CbTp panels (UNmasked)
#pragma unroll
        for (int p = 0; p < 4; ++p) {
            int idx = p * 256 + t;
            int cb32 = idx >> 9, rem = idx & 511;
            int d = rem >> 2, lg = rem & 3;
            int cl0 = cb32 * 32 + lg * 8;
            bf16x8 v;
#pragma unroll
            for (int j = 0; j < 8; ++j) v[j] = (bf16)lds[cl0 + j][d];
            size_t off = ((size_t)((b * 64 + ct * 2 + cb32) * 128 + d)) * 32 + lg * 8;
            *(bf16x8*)(CbTp + off) = v;
        }
        // out block 0: exact fp32 C^T, NT stores (never re-read)
#pragma unroll
        for (int p = 0; p < 8; ++p) {
            int d = p * 16 + (t >> 4);
            int cl = (t & 15) * 4;
            f32x4 v = {lds[cl][d], lds[cl + 1][d], lds[cl + 2][d], lds[cl + 3][d]};
            __builtin_nontemporal_store(v,
                (f32x4*)(out + ((size_t)(b * 512 + d)) * LC + c0 + cl));
        }
    } else {
        int idx0 = blockIdx.x - 2048;
        int b = idx0 >> 2, qt = idx0 & 3;
        int q0 = qt * 64;
        bf16* ldsb = (bf16*)lds;   // reuse as bf16 [64][132]
        int r = t >> 2, cb = (t & 3) * 32;
        size_t rowoff = ((size_t)(b * LQ + q0 + r)) * DD + cb;
        const float4* src = (const float4*)(Q + rowoff);
        float s1 = 0.f;
#pragma unroll
        for (int i = 0; i < 8; ++i) {
            float4 v = src[i];
            int d = cb + i * 4;
            ldsb[r * 132 + d] = (bf16)v.x; ldsb[r * 132 + d + 1] = (bf16)v.y;
            ldsb[r * 132 + d + 2] = (bf16)v.z; ldsb[r * 132 + d + 3] = (bf16)v.w;
            s1 += v.x * w4Q[d] + v.y * w4Q[d + 1] + v.z * w4Q[d + 2] + v.w * w4Q[d + 3];
        }
        s1 += __shfl_xor(s1, 1);
        s1 += __shfl_xor(s1, 2);
        if ((t & 3) == 0) sub1[b * LQ + q0 + r] = s1;
        __syncthreads();

#pragma unroll
        for (int p = 0; p < 4; ++p) {
            int idx = p * 256 + t;
            int chunk = idx >> 6, w = idx & 63;
            int qb_l = chunk >> 2, ks = chunk & 3;
            int lr = w & 15, lg = w >> 4;
            bf16x8 v = *(bf16x8*)&ldsb[(qb_l * 16 + lr) * 132 + ks * 32 + lg * 8];
            size_t off = ((size_t)((b * 16 + qt * 4 + qb_l) * 4 + ks)) * 512 + w * 8;
            *(bf16x8*)(Qbp + off) = v;
        }
#pragma unroll
        for (int p = 0; p < 4; ++p) {
            int idx = p * 256 + t;
            int chunk = idx >> 6, w = idx & 63;
            int ks_l = chunk >> 3, dt = chunk & 7;
            int lr = w & 15, lg = w >> 4;
            int d = dt * 16 + lr, ql = ks_l * 32 + lg * 8;
            bf16x8 v;
#pragma unroll
            for (int j = 0; j < 8; ++j) v[j] = ldsb[(ql + j) * 132 + d];
            size_t off = ((size_t)((b * 8 + qt * 2 + ks_l) * 8 + dt)) * 512 + w * 8;
            *(bf16x8*)(QbTp + off) = v;
        }
    }
}

// ---------------------------------------------------------------------------
// K2 (fused k_s + k_m): block = (qt: 64 q, ksl: 512 c), 4 subtiles of 128 c.
// grid 1024 1D (XCD-swizzled, same-b co-located); 4 waves; LDS 38.4 KB.
// ---------------------------------------------------------------------------
__global__ __launch_bounds__(256) void k_sm(const bf16* __restrict__ Cwp,
    const bf16* __restrict__ Qbp, const bf16* __restrict__ CbTp,
    const float* __restrict__ sub0, const float* __restrict__ sub1,
    const float* __restrict__ Qmask, const float* __restrict__ Cmask,
    const float* __restrict__ bias,
    bf16* __restrict__ Pp, float* __restrict__ Rpart, float* __restrict__ Lpart,
    bf16* __restrict__ MTp)
{
    __shared__ bf16 ldsP[128][82];    // [c_local][q_local]
    __shared__ bf16 ldsPT[64][136];   // [q_local][c_local]
    int id = blockIdx.x;
    int xcd = id & 7, slot = id >> 3;            // same-b -> same XCD
    int b = xcd * 8 + (slot >> 4);
    int rem = slot & 15;
    int qt = rem & 3, ksl = rem >> 2;
    int q0 = qt * 64;
    int t = threadIdx.x, wid = t >> 6, lane = t & 63;
    int lr = lane & 15, lg = lane >> 4;
    int dbase = wid * 32;

    float biasv = bias[0];
    float s1v[4], qmv[4];
#pragma unroll
    for (int ct = 0; ct < 4; ++ct) {
        int q = q0 + ct * 16 + lr;
        s1v[ct] = sub1[b * LQ + q] + biasv;
        qmv[ct] = Qmask[b * LQ + q];
    }

    f32x4 accM[2][4];
#pragma unroll
    for (int rt = 0; rt < 2; ++rt)
#pragma unroll
        for (int ct = 0; ct < 4; ++ct) accM[rt][ct] = (f32x4){0.f, 0.f, 0.f, 0.f};

    const bf16* Am_base = CbTp + ((size_t)(b * 64 + ksl * 16) * 128 + dbase + lr) * 32 + lg * 8;
    const float* Mb = Cmask + b * LC + ksl * 512 + lg * 8;
    const bf16* Bb = Qbp + ((size_t)((b * 16 + qt * 4) * 4)) * 512 + lane * 8;

    for (int st = 0; st < 4; ++st) {
        int ctile = ksl * 4 + st;
        int rowbase = ctile * 128 + wid * 32;

        // ---- S GEMM (128c x 64q) ----
        f32x4 acc[2][4];
#pragma unroll
        for (int rt = 0; rt < 2; ++rt)
#pragma unroll
            for (int ct = 0; ct < 4; ++ct) acc[rt][ct] = (f32x4){0.f, 0.f, 0.f, 0.f};
        const bf16* Ab = Cwp + ((size_t)((b * 128 + ctile * 8 + wid * 2) * 4)) * 512 + lane * 8;
#pragma unroll
        for (int ks = 0; ks < 4; ++ks) {
            bf16x8 a0 = *(const bf16x8*)(Ab + (size_t)ks * 512);
            bf16x8 a1 = *(const bf16x8*)(Ab + (size_t)(4 + ks) * 512);
#pragma unroll
            for (int ct = 0; ct < 4; ++ct) {
                bf16x8 bb = *(const bf16x8*)(Bb + (size_t)(ct * 4 + ks) * 512);
                acc[0][ct] = MFMA16(a0, bb, acc[0][ct]);
                acc[1][ct] = MFMA16(a1, bb, acc[1][ct]);
            }
        }

        float sub0v[2][4], cmv[2][4];
#pragma unroll
        for (int rt = 0; rt < 2; ++rt)
#pragma unroll
            for (int j = 0; j < 4; ++j) {
                int idx = b * LC + rowbase + rt * 16 + lg * 4 + j;
                sub0v[rt][j] = sub0[idx];
                cmv[rt][j] = Cmask[idx];
            }

        // wait for previous subtile's LDS consumers
        __syncthreads();

        float rsum[2][4] = {};
#pragma unroll
        for (int ct = 0; ct < 4; ++ct) {
            float colsum = 0.f;
#pragma unroll
            for (int rt = 0; rt < 2; ++rt) {
                bf16x4 ptv;
#pragma unroll
                for (int j = 0; j < 4; ++j) {
                    float S = acc[rt][ct][j] + sub0v[rt][j] + s1v[ct];
                    float Pv = __expf(S - 8.0f) * qmv[ct];
                    rsum[rt][j] += Pv;
                    colsum += Pv * cmv[rt][j];
                    bf16 pb = (bf16)Pv;
                    ldsP[wid * 32 + rt * 16 + lg * 4 + j][ct * 16 + lr] = pb;
                    ptv[j] = pb;
                }
                *(bf16x4*)&ldsPT[ct * 16 + lr][wid * 32 + rt * 16 + lg * 4] = ptv;
            }
            colsum += __shfl_xor(colsum, 16);
            colsum += __shfl_xor(colsum, 32);
            if (lg == 0)
                Lpart[((size_t)(b * 64 + ctile * 4 + wid)) * LQ + q0 + ct * 16 + lr] = colsum;
        }
#pragma unroll
        for (int rt = 0; rt < 2; ++rt)
#pragma unroll
            for (int j = 0; j < 4; ++j) {
                float s = rsum[rt][j];
                s += __shfl_xor(s, 1);
                s += __shfl_xor(s, 2);
                s += __shfl_xor(s, 4);
                s += __shfl_xor(s, 8);
                if (lr == 0)
                    Rpart[((size_t)(b * 4 + qt)) * LC + rowbase + rt * 16 + lg * 4 + j] = s;
            }
        __syncthreads();

        // ---- Pp panel store (16 chunks: cb_l 0..7, ks_l 0..1) ----
#pragma unroll
        for (int p = 0; p < 4; ++p) {
            int idx = p * 256 + t;
            int chunk = idx >> 6, w = idx & 63;
            int cb_l = chunk >> 1, ks_l = chunk & 1;
            int plr = w & 15, plg = w >> 4;
            bf16x8 v = *(bf16x8*)&ldsP[cb_l * 16 + plr][ks_l * 32 + plg * 8];
            size_t off = ((size_t)((b * 128 + ctile * 8 + cb_l) * 8 + qt * 2 + ks_l)) * 512 + w * 8;
            *(bf16x8*)(Pp + off) = v;
        }

        // ---- M GEMM accumulate from ldsPT: K = this subtile's 128 c ----
#pragma unroll
        for (int kf = 0; kf < 4; ++kf) {
            int ks = st * 4 + kf;
            bf16x8 a0 = *(const bf16x8*)(Am_base + (size_t)ks * 4096);
            bf16x8 a1 = *(const bf16x8*)(Am_base + (size_t)ks * 4096 + 512);
            f32x4 m0 = *(const f32x4*)(Mb + ks * 32);
            f32x4 m1 = *(const f32x4*)(Mb + ks * 32 + 4);
            bf16x8 msk;
#pragma unroll
            for (int i = 0; i < 4; ++i) { msk[i] = (bf16)m0[i]; msk[4 + i] = (bf16)m1[i]; }
            a0 = a0 * msk;
            a1 = a1 * msk;
#pragma unroll
            for (int ct = 0; ct < 4; ++ct) {
                bf16x8 bb = *(bf16x8*)&ldsPT[ct * 16 + lr][kf * 32 + lg * 8];
                accM[0][ct] = MFMA16(a0, bb, accM[0][ct]);
                accM[1][ct] = MFMA16(a1, bb, accM[1][ct]);
            }
        }
    }

    // ---- MTp slice store (native flat layout) ----
    size_t base = ((((size_t)ksl * B_ + b) * 4 + qt) * 4 + wid) * 2048;
#pragma unroll
    for (int rt = 0; rt < 2; ++rt)
#pragma unroll
        for (int ct = 0; ct < 4; ++ct)
#pragma unroll
            for (int j = 0; j < 4; ++j)
                MTp[base + (size_t)(rt * 16 + ct * 4 + j) * 64 + lane] = (bf16)accM[rt][ct][j];
}

// ---------------------------------------------------------------------------
// K3: reduce 4 K-slices + fold Linv -> MTpn (lane-linear chunks)
// grid 1024 1D (XCD-swizzled: b-local reads of MTp/Lpart, b-local MTpn writes);
// 4 blocks/CU (was 1) -> latency hidden.
// ---------------------------------------------------------------------------
__global__ __launch_bounds__(256) void k_m2(const bf16* __restrict__ MTp,
    const float* __restrict__ Lpart, bf16* __restrict__ MTpn)
{
    __shared__ float ldsLinv[256];
    int id = blockIdx.x;
    int xcd = id & 7, slot9 = id >> 3;           // same-b -> same XCD
    int b = xcd * 8 + (slot9 >> 4);
    int ih = slot9 & 15;                          // 0..15
    int t = threadIdx.x;
    {
        float s = 0.f;
#pragma unroll
        for (int sl = 0; sl < 64; ++sl) s += Lpart[((size_t)(b * 64 + sl)) * LQ + t];
        ldsLinv[t] = 1.0f / fmaxf(s, 1e-30f);
    }
    __syncthreads();
    {
        int slot = ih * 256 + t;    // 0..4095
        int d = slot >> 5, qo = slot & 31;
        int q0 = qo * 8;
        int qt = q0 >> 6, ct = (q0 >> 4) & 3, lr0 = q0 & 15;
        int wid = d >> 5, rt = (d >> 4) & 1, lgd = (d >> 2) & 3, j = d & 3;
        size_t roff = ((size_t)(b * 4 + qt)) * 8192 + wid * 2048
                      + (rt * 16 + ct * 4 + j) * 64 + lgd * 16 + lr0;
        float a8[8] = {0.f, 0.f, 0.f, 0.f, 0.f, 0.f, 0.f, 0.f};
#pragma unroll
        for (int sl = 0; sl < 4; ++sl) {
            bf16x8 x = *(const bf16x8*)(MTp + (size_t)sl * B_ * 32768 + roff);
#pragma unroll
            for (int k = 0; k < 8; ++k) a8[k] += (float)x[k];
        }
        bf16x8 o;
#pragma unroll
        for (int k = 0; k < 8; ++k) o[k] = (bf16)(a8[k] * ldsLinv[q0 + k]);
        size_t woff = ((size_t)((b * 8 + (qo >> 2)) * 8 + (d >> 4))) * 512
                      + ((qo & 3) * 16 + (d & 15)) * 8;
        *(bf16x8*)(MTpn + woff) = o;
    }
}

// ---------------------------------------------------------------------------
// K4: A = Rinv*(P@Qb), Bt = Rinv*(P@M). C from CbTp (bf16), prefetched.
//   NT stores for out blocks 1-3; plain loads. grid 2048 1D (XCD-swizzled)
// ---------------------------------------------------------------------------
__global__ __launch_bounds__(256) void k_out(const bf16* __restrict__ Pp,
    const bf16* __restrict__ QbTp, const bf16* __restrict__ MTpn,
    const bf16* __restrict__ CbTp, const float* __restrict__ Rpart,
    float* __restrict__ out)
{
    __shared__ f32x4 smem4[2304];                       // 36864 B
    bf16* stage = (bf16*)smem4;                         // stage[2][8192] (32 KB)
    bf16 (*ldsA)[72] = (bf16(*)[72])smem4;              // epilogue-only (union)
    bf16 (*ldsB)[72] = (bf16(*)[72])((char*)smem4 + 18432);

    int id = blockIdx.x;
    int xcd = id & 7, slot = id >> 3;            // same-b -> same XCD
    int b = xcd * 8 + (slot >> 5);
    int ctile = slot & 31;
    int t = threadIdx.x, wid = t >> 6, lane = t & 63;
    int lr = lane & 15, lg = lane >> 4;
    int c0 = ctile * 64;

    const bf16* gsrc = (wid < 2 ? QbTp : MTpn) + (size_t)b * 32768
                       + (size_t)(wid & 1) * 2048 + lane * 8;
    int ldst = wid * 2048 + lane * 8;

    f32x4 rs = (f32x4){0.f, 0.f, 0.f, 0.f};
#pragma unroll
    for (int s = 0; s < 4; ++s)
        rs += *(const f32x4*)(Rpart + ((size_t)(b * 4 + s)) * LC + c0 + wid * 16 + lg * 4);
    f32x4 rv;
#pragma unroll
    for (int j = 0; j < 4; ++j) rv[j] = 1.0f / fmaxf(rs[j], 1e-30f);

    f32x4 accA[8], accB[8];
#pragma unroll
    for (int dt = 0; dt < 8; ++dt) {
        accA[dt] = (f32x4){0.f, 0.f, 0.f, 0.f};
        accB[dt] = (f32x4){0.f, 0.f, 0.f, 0.f};
    }
    const bf16* Ab = Pp + ((size_t)((b * 128 + ctile * 4 + wid) * 8)) * 512 + lane * 8;

    {
        bf16x8 g0 = *(const bf16x8*)(gsrc);
        bf16x8 g1 = *(const bf16x8*)(gsrc + 512);
        bf16x8 g2 = *(const bf16x8*)(gsrc + 1024);
        bf16x8 g3 = *(const bf16x8*)(gsrc + 1536);
        *(bf16x8*)&stage[ldst]        = g0;
        *(bf16x8*)&stage[ldst + 512]  = g1;
        *(bf16x8*)&stage[ldst + 1024] = g2;
        *(bf16x8*)&stage[ldst + 1536] = g3;
    }
    __syncthreads();

    for (int ks = 0; ks < 8; ++ks) {
        int cur = (ks & 1) * 8192;
        bf16x8 g0, g1, g2, g3;
        if (ks < 7) {
            const bf16* gs = gsrc + (size_t)(ks + 1) * 4096;
            g0 = *(const bf16x8*)(gs);
            g1 = *(const bf16x8*)(gs + 512);
            g2 = *(const bf16x8*)(gs + 1024);
            g3 = *(const bf16x8*)(gs + 1536);
        }
        bf16x8 a = *(const bf16x8*)(Ab + (size_t)ks * 512);
        int foff = cur + lane * 8;
#pragma unroll
        for (int dt = 0; dt < 8; ++dt) {
            bf16x8 bq = *(bf16x8*)&stage[foff + dt * 512];
            bf16x8 bm = *(bf16x8*)&stage[foff + 4096 + dt * 512];
            accA[dt] = MFMA16(a, bq, accA[dt]);
            accB[dt] = MFMA16(a, bm, accB[dt]);
        }
        if (ks < 7) {
            int nb = cur ^ 8192;
            *(bf16x8*)&stage[nb + ldst]        = g0;
            *(bf16x8*)&stage[nb + ldst + 512]  = g1;
            *(bf16x8*)&stage[nb + ldst + 1024] = g2;
            *(bf16x8*)&stage[nb + ldst + 1536] = g3;
        }
        __syncthreads();
    }

    // prefetch epilogue C^T (independent of LDS; overlaps transpose phase)
    int fsub = t >> 4;
    int cq = (t & 15) * 4;
    int cglob = c0 + cq;
    int cb32g = cglob >> 5, cig = cglob & 31;
    bf16x4 cpre[8];
#pragma unroll
    for (int pass = 0; pass < 8; ++pass) {
        int d = pass * 16 + fsub;
        cpre[pass] = *(const bf16x4*)(CbTp + ((size_t)(b * 64 + cb32g) * 128 + d) * 32 + cig);
    }

#pragma unroll
    for (int dt = 0; dt < 8; ++dt) {
        f32x4 a4 = accA[dt] * rv;
        f32x4 b4 = accB[dt] * rv;
        bf16x4 pa = { (bf16)a4[0], (bf16)a4[1], (bf16)a4[2], (bf16)a4[3] };
        bf16x4 pb = { (bf16)b4[0], (bf16)b4[1], (bf16)b4[2], (bf16)b4[3] };
        *(bf16x4*)&ldsA[dt * 16 + lr][wid * 16 + lg * 4] = pa;
        *(bf16x4*)&ldsB[dt * 16 + lr][wid * 16 + lg * 4] = pb;
    }
    __syncthreads();

    float* obase = out + ((size_t)b * 512) * LC;
#pragma unroll
    for (int pass = 0; pass < 8; ++pass) {
        int d = pass * 16 + fsub;
        bf16x4 av = *(bf16x4*)&ldsA[d][cq];
        bf16x4 bv = *(bf16x4*)&ldsB[d][cq];
        bf16x4 cb4 = cpre[pass];
        f32x4 c4 = {(float)cb4[0], (float)cb4[1], (float)cb4[2], (float)cb4[3]};
        f32x4 a4 = {(float)av[0], (float)av[1], (float)av[2], (float)av[3]};
        f32x4 b4 = {(float)bv[0], (float)bv[1], (float)bv[2], (float)bv[3]};
        __builtin_nontemporal_store(a4, (f32x4*)(obase + (size_t)(128 + d) * LC + c0 + cq));
        __builtin_nontemporal_store(c4 * a4, (f32x4*)(obase + (size_t)(256 + d) * LC + c0 + cq));
        __builtin_nontemporal_store(c4 * b4, (f32x4*)(obase + (size_t)(384 + d) * LC + c0 + cq));
    }
}

// ---------------------------------------------------------------------------
extern "C" void kernel_launch(void* const* d_in, const int* in_sizes, int n_in,
                              void* d_out, int out_size, void* d_ws, size_t ws_size,
                              hipStream_t stream)
{
    const float* C     = (const float*)d_in[0];
    const float* Q     = (const float*)d_in[1];
    const float* Cmask = (const float*)d_in[2];
    const float* Qmask = (const float*)d_in[3];
    const float* w4C   = (const float*)d_in[4];
    const float* w4Q   = (const float*)d_in[5];
    const float* w4mlu = (const float*)d_in[6];
    const float* bias  = (const float*)d_in[7];
    float* out = (float*)d_out;

    char* ws = (char*)d_ws;
    size_t off = 0;
    auto alloc = [&](size_t bytes) -> char* {
        char* p = ws + off;
        off += (bytes + 255) & ~(size_t)255;
        return p;
    };
    bf16* Cwp   = (bf16*)alloc((size_t)B_ * LC * DD * 2);
    bf16* CbTp  = (bf16*)alloc((size_t)B_ * LC * DD * 2);
    bf16* Qbp   = (bf16*)alloc((size_t)B_ * LQ * DD * 2);
    bf16* QbTp  = (bf16*)alloc((size_t)B_ * LQ * DD * 2);
    bf16* Pp    = (bf16*)alloc((size_t)B_ * LC * LQ * 2);
    bf16* MTp   = (bf16*)alloc((size_t)4 * B_ * DD * LQ * 2);
    bf16* MTpn  = (bf16*)alloc((size_t)B_ * DD * LQ * 2);
    float* sub0 = (float*)alloc((size_t)B_ * LC * 4);
    float* sub1 = (float*)alloc((size_t)B_ * LQ * 4);
    float* Rpart = (float*)alloc((size_t)B_ * 4 * LC * 4);
    float* Lpart = (float*)alloc((size_t)B_ * 64 * LQ * 4);
    (void)ws_size; (void)in_sizes; (void)n_in; (void)out_size;

    hipLaunchKernelGGL(k_prep, dim3(2304), dim3(256), 0, stream,
                       C, Q, w4C, w4Q, w4mlu, Cwp, CbTp, Qbp, QbTp, sub0, sub1, out);
    hipLaunchKernelGGL(k_sm, dim3(1024), dim3(256), 0, stream,
                       Cwp, Qbp, CbTp, sub0, sub1, Qmask, Cmask, bias,
                       Pp, Rpart, Lpart, MTp);
    hipLaunchKernelGGL(k_m2, dim3(1024), dim3(256), 0, stream, MTp, Lpart, MTpn);
    hipLaunchKernelGGL(k_out, dim3(2048), dim3(256), 0, stream,
                       Pp, QbTp, MTpn, CbTp, Rpart, out);
}